// Round 1
// baseline (961.373 us; speedup 1.0000x reference)
//
#include <hip/hip_runtime.h>

#define T_SEQ 4096
#define C_EMB 2048
#define NH 16
#define NKV 4
#define HD 128

typedef short bf16x8 __attribute__((ext_vector_type(8)));
typedef float f32x4 __attribute__((ext_vector_type(4)));
typedef unsigned short u16x4 __attribute__((ext_vector_type(4)));

__device__ inline unsigned short f2bf(float f) {
    unsigned int u = __float_as_uint(f);
    unsigned int r = (u + 0x7FFFu + ((u >> 16) & 1u)) >> 16;
    return (unsigned short)r;
}

// ---------------- fp32 -> bf16 elementwise ----------------
__global__ __launch_bounds__(256) void cvt_bf16(const float* __restrict__ in,
                                                unsigned short* __restrict__ out, int n) {
    int i = (blockIdx.x * 256 + threadIdx.x) * 4;
    if (i >= n) return;
    float4 f = *(const float4*)(&in[i]);
    u16x4 o;
    o.x = f2bf(f.x); o.y = f2bf(f.y); o.z = f2bf(f.z); o.w = f2bf(f.w);
    *(u16x4*)(&out[i]) = o;
}

// ---------------- fp32 [R][Cc] (ld_in) -> bf16 [Cc][R] (ld_out) ----------------
__global__ __launch_bounds__(256) void transpose_cvt(const float* __restrict__ in, int ld_in,
                                                     int R, int Cc,
                                                     unsigned short* __restrict__ out, int ld_out) {
    __shared__ float tile[32][33];
    int x = blockIdx.x * 32 + threadIdx.x;         // col in input
    for (int i = threadIdx.y; i < 32; i += 8) {
        int y = blockIdx.y * 32 + i;               // row in input
        tile[i][threadIdx.x] = in[(size_t)y * ld_in + x];
    }
    __syncthreads();
    int xo = blockIdx.y * 32 + threadIdx.x;        // out col (= input row)
    for (int i = threadIdx.y; i < 32; i += 8) {
        int yo = blockIdx.x * 32 + i;              // out row (= input col)
        out[(size_t)yo * ld_out + xo] = f2bf(tile[threadIdx.x][i]);
    }
}

// ---------------- bf16 GEMM: C[M][N] = A[M][K] * Bt[N][K]^T, fp32 out ----------------
// 128x128 tile, 4 waves (2x2), each wave 64x64 = 4x4 MFMA tiles, BK=32.
// LDS rows padded to 40 bf16 (80 B) -> <=2-way bank aliasing (free).
__global__ __launch_bounds__(256) void gemm_bt(const unsigned short* __restrict__ A,
                                               const unsigned short* __restrict__ Bt,
                                               float* __restrict__ C, int M, int N, int K) {
    __shared__ __align__(16) unsigned short As[128 * 40];
    __shared__ __align__(16) unsigned short Bs[128 * 40];
    int t = threadIdx.x;
    int wave = t >> 6, lane = t & 63;
    int ln = lane & 15, q = lane >> 4;
    int wm = (wave >> 1) * 64, wn = (wave & 1) * 64;
    int m0 = blockIdx.y * 128, n0 = blockIdx.x * 128;

    f32x4 acc[4][4] = {};

    for (int k0 = 0; k0 < K; k0 += 32) {
        __syncthreads();
#pragma unroll
        for (int s = 0; s < 2; ++s) {
            int id = t + s * 256;
            int r = id >> 2, c = id & 3;
            *(int4*)(&As[r * 40 + c * 8]) = *(const int4*)(&A[(size_t)(m0 + r) * K + k0 + c * 8]);
            *(int4*)(&Bs[r * 40 + c * 8]) = *(const int4*)(&Bt[(size_t)(n0 + r) * K + k0 + c * 8]);
        }
        __syncthreads();
        bf16x8 af[4], bfr[4];
#pragma unroll
        for (int i = 0; i < 4; ++i) af[i] = *(const bf16x8*)(&As[(wm + i * 16 + ln) * 40 + q * 8]);
#pragma unroll
        for (int j = 0; j < 4; ++j) bfr[j] = *(const bf16x8*)(&Bs[(wn + j * 16 + ln) * 40 + q * 8]);
#pragma unroll
        for (int i = 0; i < 4; ++i)
#pragma unroll
            for (int j = 0; j < 4; ++j)
                acc[i][j] = __builtin_amdgcn_mfma_f32_16x16x32_bf16(af[i], bfr[j], acc[i][j], 0, 0, 0);
    }
#pragma unroll
    for (int i = 0; i < 4; ++i)
#pragma unroll
        for (int j = 0; j < 4; ++j)
#pragma unroll
            for (int r = 0; r < 4; ++r) {
                int row = m0 + wm + i * 16 + q * 4 + r;
                int col = n0 + wn + j * 16 + ln;
                C[(size_t)row * N + col] = acc[i][j][r];
            }
}

// ---------------- RoPE + RMSNorm: one wave per (token, head) ----------------
// heads 0..15 -> Q (scaled by 1/sqrt(HD)), heads 16..19 -> K
__global__ __launch_bounds__(256) void rope_rms(const float* __restrict__ QKV,
                                                const float* __restrict__ cosb,
                                                const float* __restrict__ sinb,
                                                unsigned short* __restrict__ Qn,
                                                unsigned short* __restrict__ Kn) {
    int gw = blockIdx.x * 4 + (threadIdx.x >> 6);
    int lane = threadIdx.x & 63;
    int t = gw / 20;
    int h = gw % 20;
    const float* v = QKV + (size_t)t * 3072 + h * 128;  // 16*128 == 2048, so K heads line up too
    float a = v[lane];
    float b = v[lane + 64];
    float cc = cosb[t * 64 + lane];
    float ss = sinb[t * 64 + lane];
    float y1 = a * cc + b * ss;
    float y2 = b * cc - a * ss;
    float sq = y1 * y1 + y2 * y2;
#pragma unroll
    for (int off = 1; off < 64; off <<= 1) sq += __shfl_xor(sq, off);
    float r = rsqrtf(sq * (1.0f / 128.0f) + 1e-6f);
    if (h < 16) {
        float s = r * 0.08838834764831845f;  // fold 1/sqrt(HD) into Q
        unsigned short* o = Qn + (size_t)t * 2048 + h * 128;
        o[lane] = f2bf(y1 * s);
        o[lane + 64] = f2bf(y2 * s);
    } else {
        unsigned short* o = Kn + (size_t)t * 512 + (h - 16) * 128;
        o[lane] = f2bf(y1 * r);
        o[lane + 64] = f2bf(y2 * r);
    }
}

// ---------------- Flash attention: 1 wave per (16-row Q tile, head) ----------------
// Qn [T][2048] bf16 (pre-scaled), Kn [T][512] bf16, Vt [512][T] bf16, Ao [T][2048] bf16
__global__ __launch_bounds__(64) void flash_attn(const unsigned short* __restrict__ Qn,
                                                 const unsigned short* __restrict__ Kn,
                                                 const unsigned short* __restrict__ Vt,
                                                 unsigned short* __restrict__ Ao) {
    int bq = gridDim.x - 1 - blockIdx.x;   // longest rows first
    int h = blockIdx.y;
    int kvh = h >> 2;
    int lane = threadIdx.x;
    int ln = lane & 15, q = lane >> 4;
    int qt0 = bq * 16;

    __shared__ __align__(16) unsigned short Pl[16 * 32];

    bf16x8 qf[4];
    const unsigned short* qbase = Qn + (size_t)qt0 * 2048 + h * 128 + (size_t)ln * 2048;
#pragma unroll
    for (int kc = 0; kc < 4; ++kc) qf[kc] = *(const bf16x8*)(qbase + kc * 32 + q * 8);

    f32x4 o[8] = {};
    float m_i[4], l_i[4];
#pragma unroll
    for (int r = 0; r < 4; ++r) { m_i[r] = -1e30f; l_i[r] = 0.0f; }

    int n_tot = (qt0 + 47) >> 5;   // ceil((qt0+16)/32)
    int n_full = (qt0 + 1) >> 5;   // fully-unmasked tiles

    for (int it = 0; it < n_tot; ++it) {
        int kt0 = it * 32;
        f32x4 s[2] = {};
#pragma unroll
        for (int jn = 0; jn < 2; ++jn) {
            const unsigned short* kbase = Kn + (size_t)(kt0 + jn * 16 + ln) * 512 + kvh * 128;
#pragma unroll
            for (int kc = 0; kc < 4; ++kc) {
                bf16x8 kf = *(const bf16x8*)(kbase + kc * 32 + q * 8);
                s[jn] = __builtin_amdgcn_mfma_f32_16x16x32_bf16(qf[kc], kf, s[jn], 0, 0, 0);
            }
        }
        if (it >= n_full) {
#pragma unroll
            for (int jn = 0; jn < 2; ++jn)
#pragma unroll
                for (int r = 0; r < 4; ++r) {
                    int key = kt0 + jn * 16 + ln;
                    int row = qt0 + q * 4 + r;
                    if (key > row) s[jn][r] = -1e30f;
                }
        }
        float alpha[4];
#pragma unroll
        for (int r = 0; r < 4; ++r) {
            float v = fmaxf(s[0][r], s[1][r]);
            v = fmaxf(v, __shfl_xor(v, 1));
            v = fmaxf(v, __shfl_xor(v, 2));
            v = fmaxf(v, __shfl_xor(v, 4));
            v = fmaxf(v, __shfl_xor(v, 8));
            float mn = fmaxf(m_i[r], v);
            alpha[r] = __expf(m_i[r] - mn);
            m_i[r] = mn;
        }
#pragma unroll
        for (int r = 0; r < 4; ++r) {
            float p0 = __expf(s[0][r] - m_i[r]);
            float p1 = __expf(s[1][r] - m_i[r]);
            Pl[(q * 4 + r) * 32 + ln] = f2bf(p0);
            Pl[(q * 4 + r) * 32 + 16 + ln] = f2bf(p1);
            float v = p0 + p1;
            v += __shfl_xor(v, 1);
            v += __shfl_xor(v, 2);
            v += __shfl_xor(v, 4);
            v += __shfl_xor(v, 8);
            l_i[r] = l_i[r] * alpha[r] + v;
        }
#pragma unroll
        for (int f = 0; f < 8; ++f)
#pragma unroll
            for (int r = 0; r < 4; ++r) o[f][r] *= alpha[r];
        __syncthreads();
        bf16x8 pf = *(const bf16x8*)(&Pl[ln * 32 + q * 8]);
        const unsigned short* vbase = Vt + (size_t)(kvh * 128) * 4096 + kt0 + q * 8;
#pragma unroll
        for (int f = 0; f < 8; ++f) {
            bf16x8 vf = *(const bf16x8*)(vbase + (size_t)(f * 16 + ln) * 4096);
            o[f] = __builtin_amdgcn_mfma_f32_16x16x32_bf16(pf, vf, o[f], 0, 0, 0);
        }
        __syncthreads();
    }
#pragma unroll
    for (int r = 0; r < 4; ++r) {
        float inv = 1.0f / l_i[r];
        int row = qt0 + q * 4 + r;
        unsigned short* obase = Ao + (size_t)row * 2048 + h * 128;
#pragma unroll
        for (int f = 0; f < 8; ++f) obase[f * 16 + ln] = f2bf(o[f][r] * inv);
    }
}

extern "C" void kernel_launch(void* const* d_in, const int* in_sizes, int n_in,
                              void* d_out, int out_size, void* d_ws, size_t ws_size,
                              hipStream_t stream) {
    const float* x    = (const float*)d_in[0];
    const float* cosb = (const float*)d_in[1];
    const float* sinb = (const float*)d_in[2];
    const float* wq   = (const float*)d_in[3];
    const float* wk   = (const float*)d_in[4];
    const float* wv   = (const float*)d_in[5];
    const float* wo   = (const float*)d_in[6];
    float* out = (float*)d_out;

    // workspace layout
    char* ws = (char*)d_ws;
    float* QKV = (float*)ws;                                   // 4096*3072 fp32 = 48 MB
    unsigned short* xb    = (unsigned short*)(ws + (size_t)4096 * 3072 * 4);
    unsigned short* wqkvT = xb    + (size_t)4096 * 2048;       // [3072][2048] bf16
    unsigned short* woT   = wqkvT + (size_t)3072 * 2048;       // [2048][2048] bf16
    unsigned short* Qn    = woT   + (size_t)2048 * 2048;       // [4096][2048] bf16
    unsigned short* Kn    = Qn    + (size_t)4096 * 2048;       // [4096][512]  bf16
    unsigned short* Vt    = Kn    + (size_t)4096 * 512;        // [512][4096]  bf16
    unsigned short* Ao    = Vt    + (size_t)512 * 4096;        // [4096][2048] bf16

    // 1. convert x to bf16
    cvt_bf16<<<(4096 * 2048 / 4 + 255) / 256, 256, 0, stream>>>(x, xb, 4096 * 2048);
    // 2. transpose-convert weights: wqkvT rows = output col, cols = k
    transpose_cvt<<<dim3(64, 64), dim3(32, 8), 0, stream>>>(wq, 2048, 2048, 2048, wqkvT, 2048);
    transpose_cvt<<<dim3(16, 64), dim3(32, 8), 0, stream>>>(wk, 512, 2048, 512, wqkvT + (size_t)2048 * 2048, 2048);
    transpose_cvt<<<dim3(16, 64), dim3(32, 8), 0, stream>>>(wv, 512, 2048, 512, wqkvT + (size_t)2560 * 2048, 2048);
    transpose_cvt<<<dim3(64, 64), dim3(32, 8), 0, stream>>>(wo, 2048, 2048, 2048, woT, 2048);
    // 3. QKV projection: [4096][3072] fp32
    gemm_bt<<<dim3(24, 32), 256, 0, stream>>>(xb, wqkvT, QKV, 4096, 3072, 2048);
    // 4. V transpose -> Vt [512][4096] bf16
    transpose_cvt<<<dim3(16, 128), dim3(32, 8), 0, stream>>>(QKV + 2560, 3072, 4096, 512, Vt, 4096);
    // 5. RoPE + RMSNorm -> Qn, Kn
    rope_rms<<<4096 * 20 / 4, 256, 0, stream>>>(QKV, cosb, sinb, Qn, Kn);
    // 6. flash attention -> Ao bf16
    flash_attn<<<dim3(256, 16), 64, 0, stream>>>(Qn, Kn, Vt, Ao);
    // 7. output projection
    gemm_bt<<<dim3(16, 32), 256, 0, stream>>>(Ao, woT, out, 4096, 2048, 2048);
}

// Round 2
// 692.847 us; speedup vs baseline: 1.3876x; 1.3876x over previous
//
#include <hip/hip_runtime.h>

#define T_SEQ 4096
#define C_EMB 2048
#define NH 16
#define NKV 4
#define HD 128

typedef short bf16x8 __attribute__((ext_vector_type(8)));
typedef float f32x4 __attribute__((ext_vector_type(4)));
typedef unsigned short u16x4 __attribute__((ext_vector_type(4)));

__device__ inline unsigned short f2bf(float f) {
    unsigned int u = __float_as_uint(f);
    unsigned int r = (u + 0x7FFFu + ((u >> 16) & 1u)) >> 16;
    return (unsigned short)r;
}

// async global->LDS 16B per lane; lds base must be wave-uniform (lane*16 auto-added)
__device__ __forceinline__ void async_cp16(const unsigned short* g, unsigned short* l) {
    __builtin_amdgcn_global_load_lds((const __attribute__((address_space(1))) unsigned int*)g,
                                     (__attribute__((address_space(3))) unsigned int*)l,
                                     16, 0, 0);
}

// ---------------- fp32 -> bf16 elementwise ----------------
__global__ __launch_bounds__(256) void cvt_bf16(const float* __restrict__ in,
                                                unsigned short* __restrict__ out, int n) {
    int i = (blockIdx.x * 256 + threadIdx.x) * 4;
    if (i >= n) return;
    float4 f = *(const float4*)(&in[i]);
    u16x4 o;
    o.x = f2bf(f.x); o.y = f2bf(f.y); o.z = f2bf(f.z); o.w = f2bf(f.w);
    *(u16x4*)(&out[i]) = o;
}

// ---------------- fp32 [R][Cc] (ld_in) -> bf16 [Cc][R] (ld_out) ----------------
__global__ __launch_bounds__(256) void transpose_cvt(const float* __restrict__ in, int ld_in,
                                                     int R, int Cc,
                                                     unsigned short* __restrict__ out, int ld_out) {
    __shared__ float tile[32][33];
    int x = blockIdx.x * 32 + threadIdx.x;         // col in input
    for (int i = threadIdx.y; i < 32; i += 8) {
        int y = blockIdx.y * 32 + i;               // row in input
        tile[i][threadIdx.x] = in[(size_t)y * ld_in + x];
    }
    __syncthreads();
    int xo = blockIdx.y * 32 + threadIdx.x;        // out col (= input row)
    for (int i = threadIdx.y; i < 32; i += 8) {
        int yo = blockIdx.x * 32 + i;              // out row (= input col)
        out[(size_t)yo * ld_out + xo] = f2bf(tile[threadIdx.x][i]);
    }
}

// ---------------- bf16 GEMM: C[M][N] = A[M][K] * Bt[N][K]^T, fp32 out ----------------
// 128x128 tile, 4 waves (2x2), BK=64, global_load_lds staging, XOR-swizzled LDS
// (chunk c at row r lands at chunk index r*8 + (c ^ (r&7)) -> frag reads 2-way max = free)
__global__ __launch_bounds__(256) void gemm_bt(const unsigned short* __restrict__ A,
                                               const unsigned short* __restrict__ Bt,
                                               float* __restrict__ C, int M, int N, int K) {
    __shared__ __align__(16) unsigned short As[128 * 64];
    __shared__ __align__(16) unsigned short Bs[128 * 64];
    int t = threadIdx.x;
    int w = t >> 6, lane = t & 63;
    int ln = lane & 15, q = lane >> 4;
    int wm = (w >> 1) * 64, wn = (w & 1) * 64;
    int m0 = blockIdx.y * 128, n0 = blockIdx.x * 128;

    f32x4 acc[4][4] = {};

    for (int k0 = 0; k0 < K; k0 += 64) {
        __syncthreads();
#pragma unroll
        for (int s = 0; s < 4; ++s) {
            int L = s * 256 + t;
            int r = L >> 3;
            int c = (L & 7) ^ (r & 7);
            unsigned short* dst = (s & 2) ? ((s & 1) ? &Bs[(s - 2) * 2048 + w * 512 + 4096]
                                                     : &Bs[(s - 2) * 2048 + w * 512])
                                          : &As[s * 2048 + w * 512];
            // simpler: recompute below
            (void)dst;
            async_cp16(&A[(size_t)(m0 + r) * K + k0 + c * 8], &As[s * 2048 + w * 512]);
            async_cp16(&Bt[(size_t)(n0 + r) * K + k0 + c * 8], &Bs[s * 2048 + w * 512]);
        }
        __syncthreads();
#pragma unroll
        for (int ks = 0; ks < 2; ++ks) {
            int cs = ((ks * 4 + q) ^ (ln & 7)) * 8;
            bf16x8 af[4], bfr[4];
#pragma unroll
            for (int i = 0; i < 4; ++i) af[i] = *(const bf16x8*)(&As[(wm + i * 16 + ln) * 64 + cs]);
#pragma unroll
            for (int j = 0; j < 4; ++j) bfr[j] = *(const bf16x8*)(&Bs[(wn + j * 16 + ln) * 64 + cs]);
#pragma unroll
            for (int i = 0; i < 4; ++i)
#pragma unroll
                for (int j = 0; j < 4; ++j)
                    acc[i][j] = __builtin_amdgcn_mfma_f32_16x16x32_bf16(af[i], bfr[j], acc[i][j], 0, 0, 0);
        }
    }
#pragma unroll
    for (int i = 0; i < 4; ++i)
#pragma unroll
        for (int j = 0; j < 4; ++j)
#pragma unroll
            for (int r = 0; r < 4; ++r) {
                int row = m0 + wm + i * 16 + q * 4 + r;
                int col = n0 + wn + j * 16 + ln;
                C[(size_t)row * N + col] = acc[i][j][r];
            }
}

// ---------------- RoPE + RMSNorm: one wave per (token, head) ----------------
__global__ __launch_bounds__(256) void rope_rms(const float* __restrict__ QKV,
                                                const float* __restrict__ cosb,
                                                const float* __restrict__ sinb,
                                                unsigned short* __restrict__ Qn,
                                                unsigned short* __restrict__ Kn) {
    int gw = blockIdx.x * 4 + (threadIdx.x >> 6);
    int lane = threadIdx.x & 63;
    int t = gw / 20;
    int h = gw % 20;
    const float* v = QKV + (size_t)t * 3072 + h * 128;
    float a = v[lane];
    float b = v[lane + 64];
    float cc = cosb[t * 64 + lane];
    float ss = sinb[t * 64 + lane];
    float y1 = a * cc + b * ss;
    float y2 = b * cc - a * ss;
    float sq = y1 * y1 + y2 * y2;
#pragma unroll
    for (int off = 1; off < 64; off <<= 1) sq += __shfl_xor(sq, off);
    float r = rsqrtf(sq * (1.0f / 128.0f) + 1e-6f);
    if (h < 16) {
        float s = r * 0.08838834764831845f;  // fold 1/sqrt(HD) into Q
        unsigned short* o = Qn + (size_t)t * 2048 + h * 128;
        o[lane] = f2bf(y1 * s);
        o[lane + 64] = f2bf(y2 * s);
    } else {
        unsigned short* o = Kn + (size_t)t * 512 + (h - 16) * 128;
        o[lane] = f2bf(y1 * r);
        o[lane + 64] = f2bf(y2 * r);
    }
}

// ---------------- Flash attention v2 ----------------
// Block: 256 thr (4 waves), 128 Q rows (32/wave), head = blockIdx.y.
// K-tile 64 keys staged in LDS (swizzled), V-tile [128 hd][64 keys] staged (swizzled).
// Qn [T][2048] bf16 pre-scaled, Kn [T][512] bf16, Vt [512][T] bf16, Ao [T][2048] bf16.
__global__ __launch_bounds__(256) void flash_attn(const unsigned short* __restrict__ Qn,
                                                  const unsigned short* __restrict__ Kn,
                                                  const unsigned short* __restrict__ Vt,
                                                  unsigned short* __restrict__ Ao) {
    __shared__ __align__(16) unsigned short Ks[64 * 128];    // [key][hd] swizzled
    __shared__ __align__(16) unsigned short Vs[128 * 64];    // [hd][key] swizzled
    __shared__ __align__(16) unsigned short Pl[4][32 * 72];  // per-wave P, padded rows

    int bq = gridDim.x - 1 - blockIdx.x;   // longest rows first
    int h = blockIdx.y;
    int kvh = h >> 2;
    int t = threadIdx.x;
    int w = t >> 6, lane = t & 63;
    int ln = lane & 15, q = lane >> 4;
    int qt0 = bq * 128;
    int wq0 = qt0 + w * 32;                // wave's first Q row

    // Q fragments: 2 row tiles x 4 k-chunks
    bf16x8 qf[2][4];
#pragma unroll
    for (int i = 0; i < 2; ++i) {
        const unsigned short* qb = Qn + (size_t)(wq0 + i * 16 + ln) * 2048 + h * 128;
#pragma unroll
        for (int kc = 0; kc < 4; ++kc) qf[i][kc] = *(const bf16x8*)(qb + kc * 32 + q * 8);
    }

    f32x4 o[2][8] = {};
    float m_i[2][4], l_i[2][4];
#pragma unroll
    for (int i = 0; i < 2; ++i)
#pragma unroll
        for (int r = 0; r < 4; ++r) { m_i[i][r] = -1e30f; l_i[i][r] = 0.0f; }

    int n_iter = 2 * bq + 2;
    for (int it = 0; it < n_iter; ++it) {
        int kt0 = it * 64;
        __syncthreads();   // previous iter's LDS reads complete
        // stage K tile: 64 keys x 128 hd (256B/row = 16 chunks, chunk c -> c^(key&15))
#pragma unroll
        for (int s = 0; s < 4; ++s) {
            int L = s * 256 + t;
            int key = L >> 4;
            int c = (L & 15) ^ (key & 15);
            async_cp16(Kn + (size_t)(kt0 + key) * 512 + kvh * 128 + c * 8,
                       &Ks[s * 2048 + w * 512]);
        }
        // stage V tile transposed: 128 hd x 64 keys (128B/row = 8 chunks, c -> c^(hd&7))
#pragma unroll
        for (int s = 0; s < 4; ++s) {
            int L = s * 256 + t;
            int hd = L >> 3;
            int c = (L & 7) ^ (hd & 7);
            async_cp16(Vt + (size_t)(kvh * 128 + hd) * 4096 + kt0 + c * 8,
                       &Vs[s * 2048 + w * 512]);
        }
        __syncthreads();   // staging visible (compiler drains vmcnt before barrier)

        // QK^T: S[2 row tiles][4 key tiles]
        f32x4 sA[2][4] = {};
#pragma unroll
        for (int jt = 0; jt < 4; ++jt) {
            int key = jt * 16 + ln;
#pragma unroll
            for (int kc = 0; kc < 4; ++kc) {
                int cs = ((kc * 4 + q) ^ ln) * 8;
                bf16x8 kf = *(const bf16x8*)(&Ks[key * 128 + cs]);
                sA[0][jt] = __builtin_amdgcn_mfma_f32_16x16x32_bf16(qf[0][kc], kf, sA[0][jt], 0, 0, 0);
                sA[1][jt] = __builtin_amdgcn_mfma_f32_16x16x32_bf16(qf[1][kc], kf, sA[1][jt], 0, 0, 0);
            }
        }
        // causal mask (sentinel keeps fully-masked rows at p=0)
        if (kt0 + 63 > wq0) {
#pragma unroll
            for (int i = 0; i < 2; ++i)
#pragma unroll
                for (int jt = 0; jt < 4; ++jt)
#pragma unroll
                    for (int r = 0; r < 4; ++r) {
                        int key = kt0 + jt * 16 + ln;
                        int row = wq0 + i * 16 + q * 4 + r;
                        if (key > row) sA[i][jt][r] = -3e38f;
                    }
        }
        // online softmax + P write
#pragma unroll
        for (int i = 0; i < 2; ++i) {
            float alpha[4];
#pragma unroll
            for (int r = 0; r < 4; ++r) {
                float v = fmaxf(fmaxf(sA[i][0][r], sA[i][1][r]), fmaxf(sA[i][2][r], sA[i][3][r]));
                v = fmaxf(v, __shfl_xor(v, 1));
                v = fmaxf(v, __shfl_xor(v, 2));
                v = fmaxf(v, __shfl_xor(v, 4));
                v = fmaxf(v, __shfl_xor(v, 8));
                float mn = fmaxf(m_i[i][r], v);
                alpha[r] = __expf(m_i[i][r] - mn);
                m_i[i][r] = mn;
                float psum = 0.0f;
                int prow = (i * 16 + q * 4 + r) * 72;
#pragma unroll
                for (int jt = 0; jt < 4; ++jt) {
                    float p = __expf(sA[i][jt][r] - mn);
                    Pl[w][prow + jt * 16 + ln] = f2bf(p);
                    psum += p;
                }
                psum += __shfl_xor(psum, 1);
                psum += __shfl_xor(psum, 2);
                psum += __shfl_xor(psum, 4);
                psum += __shfl_xor(psum, 8);
                l_i[i][r] = l_i[i][r] * alpha[r] + psum;
            }
#pragma unroll
            for (int f = 0; f < 8; ++f)
#pragma unroll
                for (int r = 0; r < 4; ++r) o[i][f][r] *= alpha[r];
        }
        // PV: P (per-wave LDS, A-operand) x V (shared LDS, B-operand)
#pragma unroll
        for (int ks = 0; ks < 2; ++ks) {
            bf16x8 pa[2];
#pragma unroll
            for (int i = 0; i < 2; ++i)
                pa[i] = *(const bf16x8*)(&Pl[w][(i * 16 + ln) * 72 + ks * 32 + q * 8]);
            int cs = ((ks * 4 + q) ^ (ln & 7)) * 8;
#pragma unroll
            for (int f = 0; f < 8; ++f) {
                bf16x8 vf = *(const bf16x8*)(&Vs[(f * 16 + ln) * 64 + cs]);
                o[0][f] = __builtin_amdgcn_mfma_f32_16x16x32_bf16(pa[0], vf, o[0][f], 0, 0, 0);
                o[1][f] = __builtin_amdgcn_mfma_f32_16x16x32_bf16(pa[1], vf, o[1][f], 0, 0, 0);
            }
        }
    }
    // epilogue
#pragma unroll
    for (int i = 0; i < 2; ++i)
#pragma unroll
        for (int r = 0; r < 4; ++r) {
            float inv = 1.0f / l_i[i][r];
            int row = wq0 + i * 16 + q * 4 + r;
            unsigned short* ob = Ao + (size_t)row * 2048 + h * 128;
#pragma unroll
            for (int f = 0; f < 8; ++f) ob[f * 16 + ln] = f2bf(o[i][f][r] * inv);
        }
}

extern "C" void kernel_launch(void* const* d_in, const int* in_sizes, int n_in,
                              void* d_out, int out_size, void* d_ws, size_t ws_size,
                              hipStream_t stream) {
    const float* x    = (const float*)d_in[0];
    const float* cosb = (const float*)d_in[1];
    const float* sinb = (const float*)d_in[2];
    const float* wq   = (const float*)d_in[3];
    const float* wk   = (const float*)d_in[4];
    const float* wv   = (const float*)d_in[5];
    const float* wo   = (const float*)d_in[6];
    float* out = (float*)d_out;

    char* ws = (char*)d_ws;
    float* QKV = (float*)ws;                                   // 4096*3072 fp32
    unsigned short* xb    = (unsigned short*)(ws + (size_t)4096 * 3072 * 4);
    unsigned short* wqkvT = xb    + (size_t)4096 * 2048;       // [3072][2048]
    unsigned short* woT   = wqkvT + (size_t)3072 * 2048;       // [2048][2048]
    unsigned short* Qn    = woT   + (size_t)2048 * 2048;       // [4096][2048]
    unsigned short* Kn    = Qn    + (size_t)4096 * 2048;       // [4096][512]
    unsigned short* Vt    = Kn    + (size_t)4096 * 512;        // [512][4096]
    unsigned short* Ao    = Vt    + (size_t)512 * 4096;        // [4096][2048]

    cvt_bf16<<<(4096 * 2048 / 4 + 255) / 256, 256, 0, stream>>>(x, xb, 4096 * 2048);
    transpose_cvt<<<dim3(64, 64), dim3(32, 8), 0, stream>>>(wq, 2048, 2048, 2048, wqkvT, 2048);
    transpose_cvt<<<dim3(16, 64), dim3(32, 8), 0, stream>>>(wk, 512, 2048, 512, wqkvT + (size_t)2048 * 2048, 2048);
    transpose_cvt<<<dim3(16, 64), dim3(32, 8), 0, stream>>>(wv, 512, 2048, 512, wqkvT + (size_t)2560 * 2048, 2048);
    transpose_cvt<<<dim3(64, 64), dim3(32, 8), 0, stream>>>(wo, 2048, 2048, 2048, woT, 2048);
    gemm_bt<<<dim3(24, 32), 256, 0, stream>>>(xb, wqkvT, QKV, 4096, 3072, 2048);
    transpose_cvt<<<dim3(16, 128), dim3(32, 8), 0, stream>>>(QKV + 2560, 3072, 4096, 512, Vt, 4096);
    rope_rms<<<4096 * 20 / 4, 256, 0, stream>>>(QKV, cosb, sinb, Qn, Kn);
    flash_attn<<<dim3(32, 16), 256, 0, stream>>>(Qn, Kn, Vt, Ao);
    gemm_bt<<<dim3(16, 32), 256, 0, stream>>>(Ao, woT, out, 4096, 2048, 2048);
}

// Round 3
// 464.900 us; speedup vs baseline: 2.0679x; 1.4903x over previous
//
#include <hip/hip_runtime.h>

#define T_SEQ 4096
#define C_EMB 2048
#define NH 16
#define NKV 4
#define HD 128

typedef short bf16x8 __attribute__((ext_vector_type(8)));
typedef float f32x4 __attribute__((ext_vector_type(4)));
typedef unsigned short u16x4 __attribute__((ext_vector_type(4)));

__device__ inline unsigned short f2bf(float f) {
    unsigned int u = __float_as_uint(f);
    unsigned int r = (u + 0x7FFFu + ((u >> 16) & 1u)) >> 16;
    return (unsigned short)r;
}

// async global->LDS 16B per lane; lds base must be wave-uniform (lane*16 auto-added)
__device__ __forceinline__ void async_cp16(const unsigned short* g, unsigned short* l) {
    __builtin_amdgcn_global_load_lds((const __attribute__((address_space(1))) unsigned int*)g,
                                     (__attribute__((address_space(3))) unsigned int*)l,
                                     16, 0, 0);
}

// ---------------- fp32 -> bf16 elementwise ----------------
__global__ __launch_bounds__(256) void cvt_bf16(const float* __restrict__ in,
                                                unsigned short* __restrict__ out, int n) {
    int i = (blockIdx.x * 256 + threadIdx.x) * 4;
    if (i >= n) return;
    float4 f = *(const float4*)(&in[i]);
    u16x4 o;
    o.x = f2bf(f.x); o.y = f2bf(f.y); o.z = f2bf(f.z); o.w = f2bf(f.w);
    *(u16x4*)(&out[i]) = o;
}

// ---------------- fp32 [R][Cc] (ld_in) -> bf16 [Cc][R] (ld_out) ----------------
__global__ __launch_bounds__(256) void transpose_cvt(const float* __restrict__ in, int ld_in,
                                                     int R, int Cc,
                                                     unsigned short* __restrict__ out, int ld_out) {
    __shared__ float tile[32][33];
    int x = blockIdx.x * 32 + threadIdx.x;
    for (int i = threadIdx.y; i < 32; i += 8) {
        int y = blockIdx.y * 32 + i;
        tile[i][threadIdx.x] = in[(size_t)y * ld_in + x];
    }
    __syncthreads();
    int xo = blockIdx.y * 32 + threadIdx.x;
    for (int i = threadIdx.y; i < 32; i += 8) {
        int yo = blockIdx.x * 32 + i;
        out[(size_t)yo * ld_out + xo] = f2bf(tile[threadIdx.x][i]);
    }
}

// ---------------- bf16 GEMM: C[M][N] = A[M][K] * Bt[N][K]^T, fp32 out ----------------
// 128x128 tile, 4 waves (2x2), BK=64, global_load_lds staging, XOR-swizzled LDS
__global__ __launch_bounds__(256) void gemm_bt(const unsigned short* __restrict__ A,
                                               const unsigned short* __restrict__ Bt,
                                               float* __restrict__ C, int M, int N, int K) {
    __shared__ __align__(16) unsigned short As[128 * 64];
    __shared__ __align__(16) unsigned short Bs[128 * 64];
    int t = threadIdx.x;
    int w = t >> 6, lane = t & 63;
    int ln = lane & 15, q = lane >> 4;
    int wm = (w >> 1) * 64, wn = (w & 1) * 64;
    int m0 = blockIdx.y * 128, n0 = blockIdx.x * 128;

    f32x4 acc[4][4] = {};

    for (int k0 = 0; k0 < K; k0 += 64) {
        __syncthreads();
#pragma unroll
        for (int s = 0; s < 4; ++s) {
            int L = s * 256 + t;
            int r = L >> 3;
            int c = (L & 7) ^ (r & 7);
            async_cp16(&A[(size_t)(m0 + r) * K + k0 + c * 8], &As[s * 2048 + w * 512]);
            async_cp16(&Bt[(size_t)(n0 + r) * K + k0 + c * 8], &Bs[s * 2048 + w * 512]);
        }
        __syncthreads();
#pragma unroll
        for (int ks = 0; ks < 2; ++ks) {
            int cs = ((ks * 4 + q) ^ (ln & 7)) * 8;
            bf16x8 af[4], bfr[4];
#pragma unroll
            for (int i = 0; i < 4; ++i) af[i] = *(const bf16x8*)(&As[(wm + i * 16 + ln) * 64 + cs]);
#pragma unroll
            for (int j = 0; j < 4; ++j) bfr[j] = *(const bf16x8*)(&Bs[(wn + j * 16 + ln) * 64 + cs]);
#pragma unroll
            for (int i = 0; i < 4; ++i)
#pragma unroll
                for (int j = 0; j < 4; ++j)
                    acc[i][j] = __builtin_amdgcn_mfma_f32_16x16x32_bf16(af[i], bfr[j], acc[i][j], 0, 0, 0);
        }
    }
#pragma unroll
    for (int i = 0; i < 4; ++i)
#pragma unroll
        for (int j = 0; j < 4; ++j)
#pragma unroll
            for (int r = 0; r < 4; ++r) {
                int row = m0 + wm + i * 16 + q * 4 + r;
                int col = n0 + wn + j * 16 + ln;
                C[(size_t)row * N + col] = acc[i][j][r];
            }
}

// ---------------- RoPE + RMSNorm: one wave per (token, head) ----------------
// Q is pre-scaled by 1/sqrt(HD) * 1/ln2 (attention runs in exp2 domain)
__global__ __launch_bounds__(256) void rope_rms(const float* __restrict__ QKV,
                                                const float* __restrict__ cosb,
                                                const float* __restrict__ sinb,
                                                unsigned short* __restrict__ Qn,
                                                unsigned short* __restrict__ Kn) {
    int gw = blockIdx.x * 4 + (threadIdx.x >> 6);
    int lane = threadIdx.x & 63;
    int t = gw / 20;
    int h = gw % 20;
    const float* v = QKV + (size_t)t * 3072 + h * 128;
    float a = v[lane];
    float b = v[lane + 64];
    float cc = cosb[t * 64 + lane];
    float ss = sinb[t * 64 + lane];
    float y1 = a * cc + b * ss;
    float y2 = b * cc - a * ss;
    float sq = y1 * y1 + y2 * y2;
#pragma unroll
    for (int off = 1; off < 64; off <<= 1) sq += __shfl_xor(sq, off);
    float r = rsqrtf(sq * (1.0f / 128.0f) + 1e-6f);
    if (h < 16) {
        float s = r * (0.08838834764831845f * 1.4426950408889634f);
        unsigned short* o = Qn + (size_t)t * 2048 + h * 128;
        o[lane] = f2bf(y1 * s);
        o[lane + 64] = f2bf(y2 * s);
    } else {
        unsigned short* o = Kn + (size_t)t * 512 + (h - 16) * 128;
        o[lane] = f2bf(y1 * r);
        o[lane + 64] = f2bf(y2 * r);
    }
}

// ---------------- Flash attention v3 ----------------
// 256 thr (4 waves). Block handles Q-tile PAIR (63-j, j): exactly 65 key-tile
// iterations for every block (perfect balance). 16 Q rows per wave per segment.
// K/V double-buffered in LDS, ONE barrier per iteration; global_load_lds issue
// and its vmcnt drain are separated by a full iteration of compute.
__global__ __launch_bounds__(256) void flash_attn(const unsigned short* __restrict__ Qn,
                                                  const unsigned short* __restrict__ Kn,
                                                  const unsigned short* __restrict__ Vt,
                                                  unsigned short* __restrict__ Ao) {
    __shared__ __align__(16) unsigned short Ks[2][64 * 128];   // [key][hd] swizzled
    __shared__ __align__(16) unsigned short Vs[2][128 * 64];   // [hd][key] swizzled
    __shared__ __align__(16) unsigned short Pl[4][16 * 72];    // per-wave P

    int pairi = blockIdx.x;                 // 0..31
    int h = blockIdx.y;
    int kvh = h >> 2;
    int t = threadIdx.x;
    int w = t >> 6, lane = t & 63;
    int ln = lane & 15, q = lane >> 4;

    int nA = 64 - pairi;                    // tiles in segment A (bq = 63-pairi)
    int bq = 63 - pairi;
    int wq0 = bq * 64 + w * 16;

    bf16x8 qf[4];
    {
        const unsigned short* qb = Qn + (size_t)(wq0 + ln) * 2048 + h * 128;
#pragma unroll
        for (int kc = 0; kc < 4; ++kc) qf[kc] = *(const bf16x8*)(qb + kc * 32 + q * 8);
    }

    f32x4 o[8] = {};
    float m_i[4], l_i[4];
#pragma unroll
    for (int r = 0; r < 4; ++r) { m_i[r] = -1e30f; l_i[r] = 0.0f; }

    // prologue: stage tile 0 into buf 0
#pragma unroll
    for (int s = 0; s < 4; ++s) {
        int L = s * 256 + t;
        int key = L >> 4;
        int c = (L & 15) ^ (key & 15);
        async_cp16(Kn + (size_t)key * 512 + kvh * 128 + c * 8, &Ks[0][s * 2048 + w * 512]);
    }
#pragma unroll
    for (int s = 0; s < 4; ++s) {
        int L = s * 256 + t;
        int hd = L >> 3;
        int c = (L & 7) ^ (hd & 7);
        async_cp16(Vt + (size_t)(kvh * 128 + hd) * 4096 + c * 8, &Vs[0][s * 2048 + w * 512]);
    }

    for (int it = 0; it < 65; ++it) {
        __syncthreads();   // drains vmcnt: tile `it` ready; prev compute on buf[(it+1)&1] done

        // issue next tile's staging (latency hidden behind this iter's compute)
        int nxt = it + 1;
        if (nxt < 65) {
            int nkt = (nxt < nA) ? nxt * 64 : (nxt - nA) * 64;
            unsigned short* kd = Ks[nxt & 1];
            unsigned short* vd = Vs[nxt & 1];
#pragma unroll
            for (int s = 0; s < 4; ++s) {
                int L = s * 256 + t;
                int key = L >> 4;
                int c = (L & 15) ^ (key & 15);
                async_cp16(Kn + (size_t)(nkt + key) * 512 + kvh * 128 + c * 8,
                           kd + s * 2048 + w * 512);
            }
#pragma unroll
            for (int s = 0; s < 4; ++s) {
                int L = s * 256 + t;
                int hd = L >> 3;
                int c = (L & 7) ^ (hd & 7);
                async_cp16(Vt + (size_t)(kvh * 128 + hd) * 4096 + nkt + c * 8,
                           vd + s * 2048 + w * 512);
            }
        }

        // segment boundary: finish A, start B
        if (it == nA) {
#pragma unroll
            for (int r = 0; r < 4; ++r) {
                float inv = 1.0f / l_i[r];
                int row = wq0 + q * 4 + r;
                unsigned short* ob = Ao + (size_t)row * 2048 + h * 128;
#pragma unroll
                for (int f = 0; f < 8; ++f) ob[f * 16 + ln] = f2bf(o[f][r] * inv);
            }
            bq = pairi;
            wq0 = bq * 64 + w * 16;
            const unsigned short* qb = Qn + (size_t)(wq0 + ln) * 2048 + h * 128;
#pragma unroll
            for (int kc = 0; kc < 4; ++kc) qf[kc] = *(const bf16x8*)(qb + kc * 32 + q * 8);
#pragma unroll
            for (int f = 0; f < 8; ++f) o[f] = (f32x4){0.f, 0.f, 0.f, 0.f};
#pragma unroll
            for (int r = 0; r < 4; ++r) { m_i[r] = -1e30f; l_i[r] = 0.0f; }
        }

        int kt0 = (it < nA) ? it * 64 : (it - nA) * 64;
        const unsigned short* kb = Ks[it & 1];
        const unsigned short* vb = Vs[it & 1];

        // QK^T
        f32x4 sA[4] = {};
#pragma unroll
        for (int jt = 0; jt < 4; ++jt) {
            int key = jt * 16 + ln;
#pragma unroll
            for (int kc = 0; kc < 4; ++kc) {
                int cs = ((kc * 4 + q) ^ ln) * 8;
                bf16x8 kf = *(const bf16x8*)(&kb[key * 128 + cs]);
                sA[jt] = __builtin_amdgcn_mfma_f32_16x16x32_bf16(qf[kc], kf, sA[jt], 0, 0, 0);
            }
        }
        // causal mask (only the diagonal tile of each segment)
        if (kt0 + 63 > wq0) {
#pragma unroll
            for (int jt = 0; jt < 4; ++jt)
#pragma unroll
                for (int r = 0; r < 4; ++r) {
                    int key = kt0 + jt * 16 + ln;
                    int row = wq0 + q * 4 + r;
                    if (key > row) sA[jt][r] = -3e38f;
                }
        }
        // online softmax (exp2 domain) + P write
        float alpha[4];
#pragma unroll
        for (int r = 0; r < 4; ++r) {
            float v = fmaxf(fmaxf(sA[0][r], sA[1][r]), fmaxf(sA[2][r], sA[3][r]));
            v = fmaxf(v, __shfl_xor(v, 1));
            v = fmaxf(v, __shfl_xor(v, 2));
            v = fmaxf(v, __shfl_xor(v, 4));
            v = fmaxf(v, __shfl_xor(v, 8));
            float mn = fmaxf(m_i[r], v);
            alpha[r] = exp2f(m_i[r] - mn);
            m_i[r] = mn;
            float psum = 0.0f;
            int prow = (q * 4 + r) * 72;
#pragma unroll
            for (int jt = 0; jt < 4; ++jt) {
                float p = exp2f(sA[jt][r] - mn);
                Pl[w][prow + jt * 16 + ln] = f2bf(p);
                psum += p;
            }
            psum += __shfl_xor(psum, 1);
            psum += __shfl_xor(psum, 2);
            psum += __shfl_xor(psum, 4);
            psum += __shfl_xor(psum, 8);
            l_i[r] = l_i[r] * alpha[r] + psum;
        }
#pragma unroll
        for (int f = 0; f < 8; ++f)
#pragma unroll
            for (int r = 0; r < 4; ++r) o[f][r] *= alpha[r];

        // PV
#pragma unroll
        for (int ks = 0; ks < 2; ++ks) {
            bf16x8 pa = *(const bf16x8*)(&Pl[w][ln * 72 + ks * 32 + q * 8]);
            int cs = ((ks * 4 + q) ^ (ln & 7)) * 8;
#pragma unroll
            for (int f = 0; f < 8; ++f) {
                bf16x8 vf = *(const bf16x8*)(&vb[(f * 16 + ln) * 64 + cs]);
                o[f] = __builtin_amdgcn_mfma_f32_16x16x32_bf16(pa, vf, o[f], 0, 0, 0);
            }
        }
    }
    // epilogue (segment B)
#pragma unroll
    for (int r = 0; r < 4; ++r) {
        float inv = 1.0f / l_i[r];
        int row = wq0 + q * 4 + r;
        unsigned short* ob = Ao + (size_t)row * 2048 + h * 128;
#pragma unroll
        for (int f = 0; f < 8; ++f) ob[f * 16 + ln] = f2bf(o[f][r] * inv);
    }
}

extern "C" void kernel_launch(void* const* d_in, const int* in_sizes, int n_in,
                              void* d_out, int out_size, void* d_ws, size_t ws_size,
                              hipStream_t stream) {
    const float* x    = (const float*)d_in[0];
    const float* cosb = (const float*)d_in[1];
    const float* sinb = (const float*)d_in[2];
    const float* wq   = (const float*)d_in[3];
    const float* wk   = (const float*)d_in[4];
    const float* wv   = (const float*)d_in[5];
    const float* wo   = (const float*)d_in[6];
    float* out = (float*)d_out;

    char* ws = (char*)d_ws;
    float* QKV = (float*)ws;                                   // 4096*3072 fp32
    unsigned short* xb    = (unsigned short*)(ws + (size_t)4096 * 3072 * 4);
    unsigned short* wqkvT = xb    + (size_t)4096 * 2048;       // [3072][2048]
    unsigned short* woT   = wqkvT + (size_t)3072 * 2048;       // [2048][2048]
    unsigned short* Qn    = woT   + (size_t)2048 * 2048;       // [4096][2048]
    unsigned short* Kn    = Qn    + (size_t)4096 * 2048;       // [4096][512]
    unsigned short* Vt    = Kn    + (size_t)4096 * 512;        // [512][4096]
    unsigned short* Ao    = Vt    + (size_t)512 * 4096;        // [4096][2048]

    cvt_bf16<<<(4096 * 2048 / 4 + 255) / 256, 256, 0, stream>>>(x, xb, 4096 * 2048);
    transpose_cvt<<<dim3(64, 64), dim3(32, 8), 0, stream>>>(wq, 2048, 2048, 2048, wqkvT, 2048);
    transpose_cvt<<<dim3(16, 64), dim3(32, 8), 0, stream>>>(wk, 512, 2048, 512, wqkvT + (size_t)2048 * 2048, 2048);
    transpose_cvt<<<dim3(16, 64), dim3(32, 8), 0, stream>>>(wv, 512, 2048, 512, wqkvT + (size_t)2560 * 2048, 2048);
    transpose_cvt<<<dim3(64, 64), dim3(32, 8), 0, stream>>>(wo, 2048, 2048, 2048, woT, 2048);
    gemm_bt<<<dim3(24, 32), 256, 0, stream>>>(xb, wqkvT, QKV, 4096, 3072, 2048);
    transpose_cvt<<<dim3(16, 128), dim3(32, 8), 0, stream>>>(QKV + 2560, 3072, 4096, 512, Vt, 4096);
    rope_rms<<<4096 * 20 / 4, 256, 0, stream>>>(QKV, cosb, sinb, Qn, Kn);
    flash_attn<<<dim3(32, 16), 256, 0, stream>>>(Qn, Kn, Vt, Ao);
    gemm_bt<<<dim3(16, 32), 256, 0, stream>>>(Ao, woT, out, 4096, 2048, 2048);
}

// Round 4
// 391.508 us; speedup vs baseline: 2.4556x; 1.1875x over previous
//
#include <hip/hip_runtime.h>

#define T_SEQ 4096
#define C_EMB 2048
#define NH 16
#define NKV 4
#define HD 128

typedef short bf16x8 __attribute__((ext_vector_type(8)));
typedef float f32x4 __attribute__((ext_vector_type(4)));
typedef unsigned short u16x4 __attribute__((ext_vector_type(4)));

__device__ inline unsigned short f2bf(float f) {
    unsigned int u = __float_as_uint(f);
    unsigned int r = (u + 0x7FFFu + ((u >> 16) & 1u)) >> 16;
    return (unsigned short)r;
}

// async global->LDS 16B per lane; lds base must be wave-uniform (lane*16 auto-added)
__device__ __forceinline__ void async_cp16(const unsigned short* g, unsigned short* l) {
    __builtin_amdgcn_global_load_lds((const __attribute__((address_space(1))) unsigned int*)g,
                                     (__attribute__((address_space(3))) unsigned int*)l,
                                     16, 0, 0);
}

// ---------------- fp32 -> bf16 elementwise ----------------
__global__ __launch_bounds__(256) void cvt_bf16(const float* __restrict__ in,
                                                unsigned short* __restrict__ out, int n) {
    int i = (blockIdx.x * 256 + threadIdx.x) * 4;
    if (i >= n) return;
    float4 f = *(const float4*)(&in[i]);
    u16x4 o;
    o.x = f2bf(f.x); o.y = f2bf(f.y); o.z = f2bf(f.z); o.w = f2bf(f.w);
    *(u16x4*)(&out[i]) = o;
}

// ---------------- fp32 [R][Cc] (ld_in) -> bf16 [Cc][R] (ld_out) ----------------
__global__ __launch_bounds__(256) void transpose_cvt(const float* __restrict__ in, int ld_in,
                                                     int R, int Cc,
                                                     unsigned short* __restrict__ out, int ld_out) {
    __shared__ float tile[32][33];
    int x = blockIdx.x * 32 + threadIdx.x;
    for (int i = threadIdx.y; i < 32; i += 8) {
        int y = blockIdx.y * 32 + i;
        tile[i][threadIdx.x] = in[(size_t)y * ld_in + x];
    }
    __syncthreads();
    int xo = blockIdx.y * 32 + threadIdx.x;
    for (int i = threadIdx.y; i < 32; i += 8) {
        int yo = blockIdx.x * 32 + i;
        out[(size_t)yo * ld_out + xo] = f2bf(tile[threadIdx.x][i]);
    }
}

// ---------------- bf16 GEMM: C[M][N] = A[M][K] * Bt[N][K]^T, fp32 out ----------------
__global__ __launch_bounds__(256) void gemm_bt(const unsigned short* __restrict__ A,
                                               const unsigned short* __restrict__ Bt,
                                               float* __restrict__ C, int M, int N, int K) {
    __shared__ __align__(16) unsigned short As[128 * 64];
    __shared__ __align__(16) unsigned short Bs[128 * 64];
    int t = threadIdx.x;
    int w = t >> 6, lane = t & 63;
    int ln = lane & 15, q = lane >> 4;
    int wm = (w >> 1) * 64, wn = (w & 1) * 64;
    int m0 = blockIdx.y * 128, n0 = blockIdx.x * 128;

    f32x4 acc[4][4] = {};

    for (int k0 = 0; k0 < K; k0 += 64) {
        __syncthreads();
#pragma unroll
        for (int s = 0; s < 4; ++s) {
            int L = s * 256 + t;
            int r = L >> 3;
            int c = (L & 7) ^ (r & 7);
            async_cp16(&A[(size_t)(m0 + r) * K + k0 + c * 8], &As[s * 2048 + w * 512]);
            async_cp16(&Bt[(size_t)(n0 + r) * K + k0 + c * 8], &Bs[s * 2048 + w * 512]);
        }
        __syncthreads();
#pragma unroll
        for (int ks = 0; ks < 2; ++ks) {
            int cs = ((ks * 4 + q) ^ (ln & 7)) * 8;
            bf16x8 af[4], bfr[4];
#pragma unroll
            for (int i = 0; i < 4; ++i) af[i] = *(const bf16x8*)(&As[(wm + i * 16 + ln) * 64 + cs]);
#pragma unroll
            for (int j = 0; j < 4; ++j) bfr[j] = *(const bf16x8*)(&Bs[(wn + j * 16 + ln) * 64 + cs]);
#pragma unroll
            for (int i = 0; i < 4; ++i)
#pragma unroll
                for (int j = 0; j < 4; ++j)
                    acc[i][j] = __builtin_amdgcn_mfma_f32_16x16x32_bf16(af[i], bfr[j], acc[i][j], 0, 0, 0);
        }
    }
#pragma unroll
    for (int i = 0; i < 4; ++i)
#pragma unroll
        for (int j = 0; j < 4; ++j)
#pragma unroll
            for (int r = 0; r < 4; ++r) {
                int row = m0 + wm + i * 16 + q * 4 + r;
                int col = n0 + wn + j * 16 + ln;
                C[(size_t)row * N + col] = acc[i][j][r];
            }
}

// ---------------- RoPE + RMSNorm: one wave per (token, head) ----------------
// Q is pre-scaled by 1/sqrt(HD) * 1/ln2 (attention runs in exp2 domain)
__global__ __launch_bounds__(256) void rope_rms(const float* __restrict__ QKV,
                                                const float* __restrict__ cosb,
                                                const float* __restrict__ sinb,
                                                unsigned short* __restrict__ Qn,
                                                unsigned short* __restrict__ Kn) {
    int gw = blockIdx.x * 4 + (threadIdx.x >> 6);
    int lane = threadIdx.x & 63;
    int t = gw / 20;
    int h = gw % 20;
    const float* v = QKV + (size_t)t * 3072 + h * 128;
    float a = v[lane];
    float b = v[lane + 64];
    float cc = cosb[t * 64 + lane];
    float ss = sinb[t * 64 + lane];
    float y1 = a * cc + b * ss;
    float y2 = b * cc - a * ss;
    float sq = y1 * y1 + y2 * y2;
#pragma unroll
    for (int off = 1; off < 64; off <<= 1) sq += __shfl_xor(sq, off);
    float r = rsqrtf(sq * (1.0f / 128.0f) + 1e-6f);
    if (h < 16) {
        float s = r * (0.08838834764831845f * 1.4426950408889634f);
        unsigned short* o = Qn + (size_t)t * 2048 + h * 128;
        o[lane] = f2bf(y1 * s);
        o[lane + 64] = f2bf(y2 * s);
    } else {
        unsigned short* o = Kn + (size_t)t * 512 + (h - 16) * 128;
        o[lane] = f2bf(y1 * r);
        o[lane + 64] = f2bf(y2 * r);
    }
}

// ---------------- Flash attention v4: fixed-max softmax ----------------
// Scores in exp2 domain are provably bounded: |s| <= 128 * 0.1275 * (1+eps) < 16.6
// (rms_norm => ||q||=||k||=sqrt(128), scale folded into Q). So init the QK^T
// accumulator to -16.6 and use p = exp2(s) directly: no running max, no alpha
// rescale, no per-iter reductions. l accumulates per-lane; one shfl-reduce per
// segment. Perfectly balanced Q-tile pairing (63-j, j): 65 iters per block.
__global__ __launch_bounds__(256) void flash_attn(const unsigned short* __restrict__ Qn,
                                                  const unsigned short* __restrict__ Kn,
                                                  const unsigned short* __restrict__ Vt,
                                                  unsigned short* __restrict__ Ao) {
    __shared__ __align__(16) unsigned short Ks[2][64 * 128];   // [key][hd] swizzled
    __shared__ __align__(16) unsigned short Vs[2][128 * 64];   // [hd][key] swizzled
    __shared__ __align__(16) unsigned short Pl[4][16 * 72];    // per-wave P

    int pairi = blockIdx.x;                 // 0..31
    int h = blockIdx.y;
    int kvh = h >> 2;
    int t = threadIdx.x;
    int w = t >> 6, lane = t & 63;
    int ln = lane & 15, q = lane >> 4;

    int nA = 64 - pairi;                    // tiles in segment A (bq = 63-pairi)
    int bq = 63 - pairi;
    int wq0 = bq * 64 + w * 16;

    bf16x8 qf[4];
    {
        const unsigned short* qb = Qn + (size_t)(wq0 + ln) * 2048 + h * 128;
#pragma unroll
        for (int kc = 0; kc < 4; ++kc) qf[kc] = *(const bf16x8*)(qb + kc * 32 + q * 8);
    }

    f32x4 o[8] = {};
    f32x4 l_p = {0.f, 0.f, 0.f, 0.f};       // per-lane partial softmax denominators

    // prologue: stage tile 0 into buf 0
#pragma unroll
    for (int s = 0; s < 4; ++s) {
        int L = s * 256 + t;
        int key = L >> 4;
        int c = (L & 15) ^ (key & 15);
        async_cp16(Kn + (size_t)key * 512 + kvh * 128 + c * 8, &Ks[0][s * 2048 + w * 512]);
    }
#pragma unroll
    for (int s = 0; s < 4; ++s) {
        int L = s * 256 + t;
        int hd = L >> 3;
        int c = (L & 7) ^ (hd & 7);
        async_cp16(Vt + (size_t)(kvh * 128 + hd) * 4096 + c * 8, &Vs[0][s * 2048 + w * 512]);
    }

    for (int it = 0; it < 65; ++it) {
        __syncthreads();   // tile `it` staged; prev compute on buf[(it+1)&1] done

        // issue next tile's staging (latency hidden behind this iter's compute)
        int nxt = it + 1;
        if (nxt < 65) {
            int nkt = (nxt < nA) ? nxt * 64 : (nxt - nA) * 64;
            unsigned short* kd = Ks[nxt & 1];
            unsigned short* vd = Vs[nxt & 1];
#pragma unroll
            for (int s = 0; s < 4; ++s) {
                int L = s * 256 + t;
                int key = L >> 4;
                int c = (L & 15) ^ (key & 15);
                async_cp16(Kn + (size_t)(nkt + key) * 512 + kvh * 128 + c * 8,
                           kd + s * 2048 + w * 512);
            }
#pragma unroll
            for (int s = 0; s < 4; ++s) {
                int L = s * 256 + t;
                int hd = L >> 3;
                int c = (L & 7) ^ (hd & 7);
                async_cp16(Vt + (size_t)(kvh * 128 + hd) * 4096 + nkt + c * 8,
                           vd + s * 2048 + w * 512);
            }
        }

        // segment boundary: finish A, start B
        if (it == nA) {
#pragma unroll
            for (int r = 0; r < 4; ++r) {
                float lsum = l_p[r];
                lsum += __shfl_xor(lsum, 1);
                lsum += __shfl_xor(lsum, 2);
                lsum += __shfl_xor(lsum, 4);
                lsum += __shfl_xor(lsum, 8);
                float inv = 1.0f / lsum;
                int row = wq0 + q * 4 + r;
                unsigned short* ob = Ao + (size_t)row * 2048 + h * 128;
#pragma unroll
                for (int f = 0; f < 8; ++f) ob[f * 16 + ln] = f2bf(o[f][r] * inv);
            }
            bq = pairi;
            wq0 = bq * 64 + w * 16;
            const unsigned short* qb = Qn + (size_t)(wq0 + ln) * 2048 + h * 128;
#pragma unroll
            for (int kc = 0; kc < 4; ++kc) qf[kc] = *(const bf16x8*)(qb + kc * 32 + q * 8);
#pragma unroll
            for (int f = 0; f < 8; ++f) o[f] = (f32x4){0.f, 0.f, 0.f, 0.f};
            l_p = (f32x4){0.f, 0.f, 0.f, 0.f};
        }

        int kt0 = (it < nA) ? it * 64 : (it - nA) * 64;
        const unsigned short* kb = Ks[it & 1];
        const unsigned short* vb = Vs[it & 1];

        // QK^T with the fixed max folded into the accumulator init
        f32x4 sA[4] = {{-16.6f, -16.6f, -16.6f, -16.6f}, {-16.6f, -16.6f, -16.6f, -16.6f},
                       {-16.6f, -16.6f, -16.6f, -16.6f}, {-16.6f, -16.6f, -16.6f, -16.6f}};
#pragma unroll
        for (int jt = 0; jt < 4; ++jt) {
            int key = jt * 16 + ln;
#pragma unroll
            for (int kc = 0; kc < 4; ++kc) {
                int cs = ((kc * 4 + q) ^ ln) * 8;
                bf16x8 kf = *(const bf16x8*)(&kb[key * 128 + cs]);
                sA[jt] = __builtin_amdgcn_mfma_f32_16x16x32_bf16(qf[kc], kf, sA[jt], 0, 0, 0);
            }
        }
        // causal mask (only the diagonal tile of each segment)
        if (kt0 + 63 > wq0) {
#pragma unroll
            for (int jt = 0; jt < 4; ++jt)
#pragma unroll
                for (int r = 0; r < 4; ++r) {
                    int key = kt0 + jt * 16 + ln;
                    int row = wq0 + q * 4 + r;
                    if (key > row) sA[jt][r] = -3e38f;
                }
        }
        // p = exp2(s), truncate to bf16, accumulate per-lane denominator
#pragma unroll
        for (int r = 0; r < 4; ++r) {
            int prow = (q * 4 + r) * 72;
#pragma unroll
            for (int jt = 0; jt < 4; ++jt) {
                float p = __builtin_amdgcn_exp2f(sA[jt][r]);
                Pl[w][prow + jt * 16 + ln] = (unsigned short)(__float_as_uint(p) >> 16);
                l_p[r] += p;
            }
        }

        // PV
#pragma unroll
        for (int ks = 0; ks < 2; ++ks) {
            bf16x8 pa = *(const bf16x8*)(&Pl[w][ln * 72 + ks * 32 + q * 8]);
            int cs = ((ks * 4 + q) ^ (ln & 7)) * 8;
#pragma unroll
            for (int f = 0; f < 8; ++f) {
                bf16x8 vf = *(const bf16x8*)(&vb[(f * 16 + ln) * 64 + cs]);
                o[f] = __builtin_amdgcn_mfma_f32_16x16x32_bf16(pa, vf, o[f], 0, 0, 0);
            }
        }
    }
    // epilogue (segment B)
#pragma unroll
    for (int r = 0; r < 4; ++r) {
        float lsum = l_p[r];
        lsum += __shfl_xor(lsum, 1);
        lsum += __shfl_xor(lsum, 2);
        lsum += __shfl_xor(lsum, 4);
        lsum += __shfl_xor(lsum, 8);
        float inv = 1.0f / lsum;
        int row = wq0 + q * 4 + r;
        unsigned short* ob = Ao + (size_t)row * 2048 + h * 128;
#pragma unroll
        for (int f = 0; f < 8; ++f) ob[f * 16 + ln] = f2bf(o[f][r] * inv);
    }
}

extern "C" void kernel_launch(void* const* d_in, const int* in_sizes, int n_in,
                              void* d_out, int out_size, void* d_ws, size_t ws_size,
                              hipStream_t stream) {
    const float* x    = (const float*)d_in[0];
    const float* cosb = (const float*)d_in[1];
    const float* sinb = (const float*)d_in[2];
    const float* wq   = (const float*)d_in[3];
    const float* wk   = (const float*)d_in[4];
    const float* wv   = (const float*)d_in[5];
    const float* wo   = (const float*)d_in[6];
    float* out = (float*)d_out;

    char* ws = (char*)d_ws;
    float* QKV = (float*)ws;                                   // 4096*3072 fp32
    unsigned short* xb    = (unsigned short*)(ws + (size_t)4096 * 3072 * 4);
    unsigned short* wqkvT = xb    + (size_t)4096 * 2048;       // [3072][2048]
    unsigned short* woT   = wqkvT + (size_t)3072 * 2048;       // [2048][2048]
    unsigned short* Qn    = woT   + (size_t)2048 * 2048;       // [4096][2048]
    unsigned short* Kn    = Qn    + (size_t)4096 * 2048;       // [4096][512]
    unsigned short* Vt    = Kn    + (size_t)4096 * 512;        // [512][4096]
    unsigned short* Ao    = Vt    + (size_t)512 * 4096;        // [4096][2048]

    cvt_bf16<<<(4096 * 2048 / 4 + 255) / 256, 256, 0, stream>>>(x, xb, 4096 * 2048);
    transpose_cvt<<<dim3(64, 64), dim3(32, 8), 0, stream>>>(wq, 2048, 2048, 2048, wqkvT, 2048);
    transpose_cvt<<<dim3(16, 64), dim3(32, 8), 0, stream>>>(wk, 512, 2048, 512, wqkvT + (size_t)2048 * 2048, 2048);
    transpose_cvt<<<dim3(16, 64), dim3(32, 8), 0, stream>>>(wv, 512, 2048, 512, wqkvT + (size_t)2560 * 2048, 2048);
    transpose_cvt<<<dim3(64, 64), dim3(32, 8), 0, stream>>>(wo, 2048, 2048, 2048, woT, 2048);
    gemm_bt<<<dim3(24, 32), 256, 0, stream>>>(xb, wqkvT, QKV, 4096, 3072, 2048);
    transpose_cvt<<<dim3(16, 128), dim3(32, 8), 0, stream>>>(QKV + 2560, 3072, 4096, 512, Vt, 4096);
    rope_rms<<<4096 * 20 / 4, 256, 0, stream>>>(QKV, cosb, sinb, Qn, Kn);
    flash_attn<<<dim3(32, 16), 256, 0, stream>>>(Qn, Kn, Vt, Ao);
    gemm_bt<<<dim3(16, 32), 256, 0, stream>>>(Ao, woT, out, 4096, 2048, 2048);
}

// Round 5
// 372.961 us; speedup vs baseline: 2.5777x; 1.0497x over previous
//
#include <hip/hip_runtime.h>

#define T_SEQ 4096
#define C_EMB 2048
#define NH 16
#define NKV 4
#define HD 128

typedef short bf16x8 __attribute__((ext_vector_type(8)));
typedef float f32x4 __attribute__((ext_vector_type(4)));
typedef unsigned short u16x4 __attribute__((ext_vector_type(4)));

__device__ inline unsigned short f2bf(float f) {
    unsigned int u = __float_as_uint(f);
    unsigned int r = (u + 0x7FFFu + ((u >> 16) & 1u)) >> 16;
    return (unsigned short)r;
}

// async global->LDS 16B per lane; lds base must be wave-uniform (lane*16 auto-added)
__device__ __forceinline__ void async_cp16(const unsigned short* g, unsigned short* l) {
    __builtin_amdgcn_global_load_lds((const __attribute__((address_space(1))) unsigned int*)g,
                                     (__attribute__((address_space(3))) unsigned int*)l,
                                     16, 0, 0);
}

// ---------------- fp32 -> bf16 elementwise ----------------
__global__ __launch_bounds__(256) void cvt_bf16(const float* __restrict__ in,
                                                unsigned short* __restrict__ out, int n) {
    int i = (blockIdx.x * 256 + threadIdx.x) * 4;
    if (i >= n) return;
    float4 f = *(const float4*)(&in[i]);
    u16x4 o;
    o.x = f2bf(f.x); o.y = f2bf(f.y); o.z = f2bf(f.z); o.w = f2bf(f.w);
    *(u16x4*)(&out[i]) = o;
}

// ---------------- fp32 [R][Cc] (ld_in) -> bf16 [Cc][R] (ld_out) ----------------
__global__ __launch_bounds__(256) void transpose_cvt(const float* __restrict__ in, int ld_in,
                                                     int R, int Cc,
                                                     unsigned short* __restrict__ out, int ld_out) {
    __shared__ float tile[32][33];
    int x = blockIdx.x * 32 + threadIdx.x;
    for (int i = threadIdx.y; i < 32; i += 8) {
        int y = blockIdx.y * 32 + i;
        tile[i][threadIdx.x] = in[(size_t)y * ld_in + x];
    }
    __syncthreads();
    int xo = blockIdx.y * 32 + threadIdx.x;
    for (int i = threadIdx.y; i < 32; i += 8) {
        int yo = blockIdx.x * 32 + i;
        out[(size_t)yo * ld_out + xo] = f2bf(tile[threadIdx.x][i]);
    }
}

// ==== Fused QKV projection + RoPE + RMSNorm ====
// C[M=4096][N=3072] = xb * wqkvT^T, 128x128 tile, BK=64, double-buffered LDS,
// ONE barrier per K-iter. Wave tiling 1x4: wave w owns rows w*32..w*32+31 and
// ALL 128 cols -> an n-block is exactly one head, so rope pairs (c, c+64) and
// the RMS row-reduction stay inside the wave. Epilogue writes Qn/Kn bf16
// (Q pre-scaled by 1/sqrt(HD)/ln2 for exp2-domain attention), V fp32 to Vbuf.
__global__ __launch_bounds__(256) void gemm_qkv(const unsigned short* __restrict__ A,
                                                const unsigned short* __restrict__ Bt,
                                                const float* __restrict__ cosb,
                                                const float* __restrict__ sinb,
                                                unsigned short* __restrict__ Qn,
                                                unsigned short* __restrict__ Kn,
                                                float* __restrict__ Vbuf) {
    __shared__ __align__(16) unsigned short As[2][128 * 64];
    __shared__ __align__(16) unsigned short Bs[2][128 * 64];
    const int K = 2048;
    int t = threadIdx.x;
    int w = t >> 6, lane = t & 63;
    int ln = lane & 15, q = lane >> 4;
    int wm = w * 32;
    int m0 = blockIdx.y * 128, n0 = blockIdx.x * 128;

    f32x4 acc[2][8] = {};

    // prologue: stage k-tile 0 into buf 0
#pragma unroll
    for (int s = 0; s < 4; ++s) {
        int L = s * 256 + t;
        int r = L >> 3;
        int c = (L & 7) ^ (r & 7);
        async_cp16(&A[(size_t)(m0 + r) * K + c * 8], &As[0][s * 2048 + w * 512]);
        async_cp16(&Bt[(size_t)(n0 + r) * K + c * 8], &Bs[0][s * 2048 + w * 512]);
    }

    for (int it = 0; it < 32; ++it) {
        __syncthreads();   // vmcnt drain: tile `it` staged; prev reads of buf[(it+1)&1] done
        if (it < 31) {
            int k0 = (it + 1) * 64;
            int p = (it + 1) & 1;
#pragma unroll
            for (int s = 0; s < 4; ++s) {
                int L = s * 256 + t;
                int r = L >> 3;
                int c = (L & 7) ^ (r & 7);
                async_cp16(&A[(size_t)(m0 + r) * K + k0 + c * 8], &As[p][s * 2048 + w * 512]);
                async_cp16(&Bt[(size_t)(n0 + r) * K + k0 + c * 8], &Bs[p][s * 2048 + w * 512]);
            }
        }
        int p = it & 1;
#pragma unroll
        for (int ks = 0; ks < 2; ++ks) {
            int cs = ((ks * 4 + q) ^ (ln & 7)) * 8;
            bf16x8 af[2], bfr[8];
#pragma unroll
            for (int i = 0; i < 2; ++i) af[i] = *(const bf16x8*)(&As[p][(wm + i * 16 + ln) * 64 + cs]);
#pragma unroll
            for (int j = 0; j < 8; ++j) bfr[j] = *(const bf16x8*)(&Bs[p][(j * 16 + ln) * 64 + cs]);
#pragma unroll
            for (int i = 0; i < 2; ++i)
#pragma unroll
                for (int j = 0; j < 8; ++j)
                    acc[i][j] = __builtin_amdgcn_mfma_f32_16x16x32_bf16(af[i], bfr[j], acc[i][j], 0, 0, 0);
        }
    }

    // ---- fused epilogue ----
    if (n0 < 2560) {
        // Q or K head: rope + rmsnorm in registers
        bool isQ = (n0 < 2048);
        int h = isQ ? (n0 >> 7) : ((n0 - 2048) >> 7);
#pragma unroll
        for (int i = 0; i < 2; ++i)
#pragma unroll
            for (int r = 0; r < 4; ++r) {
                int row = m0 + wm + i * 16 + q * 4 + r;
                float y1[4], y2[4];
                float ss = 0.0f;
#pragma unroll
                for (int j = 0; j < 4; ++j) {
                    float a = acc[i][j][r];
                    float b = acc[i][j + 4][r];
                    float cc = cosb[row * 64 + j * 16 + ln];
                    float sv = sinb[row * 64 + j * 16 + ln];
                    y1[j] = a * cc + b * sv;
                    y2[j] = b * cc - a * sv;
                    ss += y1[j] * y1[j] + y2[j] * y2[j];
                }
                ss += __shfl_xor(ss, 1);
                ss += __shfl_xor(ss, 2);
                ss += __shfl_xor(ss, 4);
                ss += __shfl_xor(ss, 8);
                float rv = rsqrtf(ss * (1.0f / 128.0f) + 1e-6f);
                if (isQ) {
                    float s = rv * (0.08838834764831845f * 1.4426950408889634f);
                    unsigned short* ob = Qn + (size_t)row * 2048 + h * 128;
#pragma unroll
                    for (int j = 0; j < 4; ++j) {
                        ob[j * 16 + ln] = f2bf(y1[j] * s);
                        ob[64 + j * 16 + ln] = f2bf(y2[j] * s);
                    }
                } else {
                    unsigned short* ob = Kn + (size_t)row * 512 + h * 128;
#pragma unroll
                    for (int j = 0; j < 4; ++j) {
                        ob[j * 16 + ln] = f2bf(y1[j] * rv);
                        ob[64 + j * 16 + ln] = f2bf(y2[j] * rv);
                    }
                }
            }
    } else {
        // V: plain fp32 store into compact [4096][512] buffer
        int v0 = n0 - 2560;
#pragma unroll
        for (int i = 0; i < 2; ++i)
#pragma unroll
            for (int j = 0; j < 8; ++j)
#pragma unroll
                for (int r = 0; r < 4; ++r) {
                    int row = m0 + wm + i * 16 + q * 4 + r;
                    Vbuf[(size_t)row * 512 + v0 + j * 16 + ln] = acc[i][j][r];
                }
    }
}

// ---------------- bf16 GEMM (out-proj): C[M][N] = A[M][K]*Bt[N][K]^T ----------------
// 128x128 tile, 2x2 wave tiling, BK=64, double-buffered, one barrier per iter.
__global__ __launch_bounds__(256) void gemm_bt_db(const unsigned short* __restrict__ A,
                                                  const unsigned short* __restrict__ Bt,
                                                  float* __restrict__ C, int M, int N, int K) {
    __shared__ __align__(16) unsigned short As[2][128 * 64];
    __shared__ __align__(16) unsigned short Bs[2][128 * 64];
    int t = threadIdx.x;
    int w = t >> 6, lane = t & 63;
    int ln = lane & 15, q = lane >> 4;
    int wm = (w >> 1) * 64, wn = (w & 1) * 64;
    int m0 = blockIdx.y * 128, n0 = blockIdx.x * 128;

    f32x4 acc[4][4] = {};

#pragma unroll
    for (int s = 0; s < 4; ++s) {
        int L = s * 256 + t;
        int r = L >> 3;
        int c = (L & 7) ^ (r & 7);
        async_cp16(&A[(size_t)(m0 + r) * K + c * 8], &As[0][s * 2048 + w * 512]);
        async_cp16(&Bt[(size_t)(n0 + r) * K + c * 8], &Bs[0][s * 2048 + w * 512]);
    }

    int niter = K >> 6;
    for (int it = 0; it < niter; ++it) {
        __syncthreads();
        if (it < niter - 1) {
            int k0 = (it + 1) * 64;
            int p = (it + 1) & 1;
#pragma unroll
            for (int s = 0; s < 4; ++s) {
                int L = s * 256 + t;
                int r = L >> 3;
                int c = (L & 7) ^ (r & 7);
                async_cp16(&A[(size_t)(m0 + r) * K + k0 + c * 8], &As[p][s * 2048 + w * 512]);
                async_cp16(&Bt[(size_t)(n0 + r) * K + k0 + c * 8], &Bs[p][s * 2048 + w * 512]);
            }
        }
        int p = it & 1;
#pragma unroll
        for (int ks = 0; ks < 2; ++ks) {
            int cs = ((ks * 4 + q) ^ (ln & 7)) * 8;
            bf16x8 af[4], bfr[4];
#pragma unroll
            for (int i = 0; i < 4; ++i) af[i] = *(const bf16x8*)(&As[p][(wm + i * 16 + ln) * 64 + cs]);
#pragma unroll
            for (int j = 0; j < 4; ++j) bfr[j] = *(const bf16x8*)(&Bs[p][(wn + j * 16 + ln) * 64 + cs]);
#pragma unroll
            for (int i = 0; i < 4; ++i)
#pragma unroll
                for (int j = 0; j < 4; ++j)
                    acc[i][j] = __builtin_amdgcn_mfma_f32_16x16x32_bf16(af[i], bfr[j], acc[i][j], 0, 0, 0);
        }
    }
#pragma unroll
    for (int i = 0; i < 4; ++i)
#pragma unroll
        for (int j = 0; j < 4; ++j)
#pragma unroll
            for (int r = 0; r < 4; ++r) {
                int row = m0 + wm + i * 16 + q * 4 + r;
                int col = n0 + wn + j * 16 + ln;
                C[(size_t)row * N + col] = acc[i][j][r];
            }
}

// ---------------- Flash attention v4: fixed-max softmax (unchanged from R4) ----------------
__global__ __launch_bounds__(256) void flash_attn(const unsigned short* __restrict__ Qn,
                                                  const unsigned short* __restrict__ Kn,
                                                  const unsigned short* __restrict__ Vt,
                                                  unsigned short* __restrict__ Ao) {
    __shared__ __align__(16) unsigned short Ks[2][64 * 128];   // [key][hd] swizzled
    __shared__ __align__(16) unsigned short Vs[2][128 * 64];   // [hd][key] swizzled
    __shared__ __align__(16) unsigned short Pl[4][16 * 72];    // per-wave P

    int pairi = blockIdx.x;                 // 0..31
    int h = blockIdx.y;
    int kvh = h >> 2;
    int t = threadIdx.x;
    int w = t >> 6, lane = t & 63;
    int ln = lane & 15, q = lane >> 4;

    int nA = 64 - pairi;                    // tiles in segment A (bq = 63-pairi)
    int bq = 63 - pairi;
    int wq0 = bq * 64 + w * 16;

    bf16x8 qf[4];
    {
        const unsigned short* qb = Qn + (size_t)(wq0 + ln) * 2048 + h * 128;
#pragma unroll
        for (int kc = 0; kc < 4; ++kc) qf[kc] = *(const bf16x8*)(qb + kc * 32 + q * 8);
    }

    f32x4 o[8] = {};
    f32x4 l_p = {0.f, 0.f, 0.f, 0.f};

#pragma unroll
    for (int s = 0; s < 4; ++s) {
        int L = s * 256 + t;
        int key = L >> 4;
        int c = (L & 15) ^ (key & 15);
        async_cp16(Kn + (size_t)key * 512 + kvh * 128 + c * 8, &Ks[0][s * 2048 + w * 512]);
    }
#pragma unroll
    for (int s = 0; s < 4; ++s) {
        int L = s * 256 + t;
        int hd = L >> 3;
        int c = (L & 7) ^ (hd & 7);
        async_cp16(Vt + (size_t)(kvh * 128 + hd) * 4096 + c * 8, &Vs[0][s * 2048 + w * 512]);
    }

    for (int it = 0; it < 65; ++it) {
        __syncthreads();

        int nxt = it + 1;
        if (nxt < 65) {
            int nkt = (nxt < nA) ? nxt * 64 : (nxt - nA) * 64;
            unsigned short* kd = Ks[nxt & 1];
            unsigned short* vd = Vs[nxt & 1];
#pragma unroll
            for (int s = 0; s < 4; ++s) {
                int L = s * 256 + t;
                int key = L >> 4;
                int c = (L & 15) ^ (key & 15);
                async_cp16(Kn + (size_t)(nkt + key) * 512 + kvh * 128 + c * 8,
                           kd + s * 2048 + w * 512);
            }
#pragma unroll
            for (int s = 0; s < 4; ++s) {
                int L = s * 256 + t;
                int hd = L >> 3;
                int c = (L & 7) ^ (hd & 7);
                async_cp16(Vt + (size_t)(kvh * 128 + hd) * 4096 + nkt + c * 8,
                           vd + s * 2048 + w * 512);
            }
        }

        if (it == nA) {
#pragma unroll
            for (int r = 0; r < 4; ++r) {
                float lsum = l_p[r];
                lsum += __shfl_xor(lsum, 1);
                lsum += __shfl_xor(lsum, 2);
                lsum += __shfl_xor(lsum, 4);
                lsum += __shfl_xor(lsum, 8);
                float inv = 1.0f / lsum;
                int row = wq0 + q * 4 + r;
                unsigned short* ob = Ao + (size_t)row * 2048 + h * 128;
#pragma unroll
                for (int f = 0; f < 8; ++f) ob[f * 16 + ln] = f2bf(o[f][r] * inv);
            }
            bq = pairi;
            wq0 = bq * 64 + w * 16;
            const unsigned short* qb = Qn + (size_t)(wq0 + ln) * 2048 + h * 128;
#pragma unroll
            for (int kc = 0; kc < 4; ++kc) qf[kc] = *(const bf16x8*)(qb + kc * 32 + q * 8);
#pragma unroll
            for (int f = 0; f < 8; ++f) o[f] = (f32x4){0.f, 0.f, 0.f, 0.f};
            l_p = (f32x4){0.f, 0.f, 0.f, 0.f};
        }

        int kt0 = (it < nA) ? it * 64 : (it - nA) * 64;
        const unsigned short* kb = Ks[it & 1];
        const unsigned short* vb = Vs[it & 1];

        f32x4 sA[4] = {{-16.6f, -16.6f, -16.6f, -16.6f}, {-16.6f, -16.6f, -16.6f, -16.6f},
                       {-16.6f, -16.6f, -16.6f, -16.6f}, {-16.6f, -16.6f, -16.6f, -16.6f}};
#pragma unroll
        for (int jt = 0; jt < 4; ++jt) {
            int key = jt * 16 + ln;
#pragma unroll
            for (int kc = 0; kc < 4; ++kc) {
                int cs = ((kc * 4 + q) ^ ln) * 8;
                bf16x8 kf = *(const bf16x8*)(&kb[key * 128 + cs]);
                sA[jt] = __builtin_amdgcn_mfma_f32_16x16x32_bf16(qf[kc], kf, sA[jt], 0, 0, 0);
            }
        }
        if (kt0 + 63 > wq0) {
#pragma unroll
            for (int jt = 0; jt < 4; ++jt)
#pragma unroll
                for (int r = 0; r < 4; ++r) {
                    int key = kt0 + jt * 16 + ln;
                    int row = wq0 + q * 4 + r;
                    if (key > row) sA[jt][r] = -3e38f;
                }
        }
#pragma unroll
        for (int r = 0; r < 4; ++r) {
            int prow = (q * 4 + r) * 72;
#pragma unroll
            for (int jt = 0; jt < 4; ++jt) {
                float p = __builtin_amdgcn_exp2f(sA[jt][r]);
                Pl[w][prow + jt * 16 + ln] = (unsigned short)(__float_as_uint(p) >> 16);
                l_p[r] += p;
            }
        }

#pragma unroll
        for (int ks = 0; ks < 2; ++ks) {
            bf16x8 pa = *(const bf16x8*)(&Pl[w][ln * 72 + ks * 32 + q * 8]);
            int cs = ((ks * 4 + q) ^ (ln & 7)) * 8;
#pragma unroll
            for (int f = 0; f < 8; ++f) {
                bf16x8 vf = *(const bf16x8*)(&vb[(f * 16 + ln) * 64 + cs]);
                o[f] = __builtin_amdgcn_mfma_f32_16x16x32_bf16(pa, vf, o[f], 0, 0, 0);
            }
        }
    }
#pragma unroll
    for (int r = 0; r < 4; ++r) {
        float lsum = l_p[r];
        lsum += __shfl_xor(lsum, 1);
        lsum += __shfl_xor(lsum, 2);
        lsum += __shfl_xor(lsum, 4);
        lsum += __shfl_xor(lsum, 8);
        float inv = 1.0f / lsum;
        int row = wq0 + q * 4 + r;
        unsigned short* ob = Ao + (size_t)row * 2048 + h * 128;
#pragma unroll
        for (int f = 0; f < 8; ++f) ob[f * 16 + ln] = f2bf(o[f][r] * inv);
    }
}

extern "C" void kernel_launch(void* const* d_in, const int* in_sizes, int n_in,
                              void* d_out, int out_size, void* d_ws, size_t ws_size,
                              hipStream_t stream) {
    const float* x    = (const float*)d_in[0];
    const float* cosb = (const float*)d_in[1];
    const float* sinb = (const float*)d_in[2];
    const float* wq   = (const float*)d_in[3];
    const float* wk   = (const float*)d_in[4];
    const float* wv   = (const float*)d_in[5];
    const float* wo   = (const float*)d_in[6];
    float* out = (float*)d_out;

    char* ws = (char*)d_ws;
    float* Vbuf = (float*)ws;                                  // [4096][512] fp32 (8 MB)
    unsigned short* xb    = (unsigned short*)(ws + (size_t)4096 * 3072 * 4);
    unsigned short* wqkvT = xb    + (size_t)4096 * 2048;       // [3072][2048]
    unsigned short* woT   = wqkvT + (size_t)3072 * 2048;       // [2048][2048]
    unsigned short* Qn    = woT   + (size_t)2048 * 2048;       // [4096][2048]
    unsigned short* Kn    = Qn    + (size_t)4096 * 2048;       // [4096][512]
    unsigned short* Vt    = Kn    + (size_t)4096 * 512;        // [512][4096]
    unsigned short* Ao    = Vt    + (size_t)512 * 4096;        // [4096][2048]

    cvt_bf16<<<(4096 * 2048 / 4 + 255) / 256, 256, 0, stream>>>(x, xb, 4096 * 2048);
    transpose_cvt<<<dim3(64, 64), dim3(32, 8), 0, stream>>>(wq, 2048, 2048, 2048, wqkvT, 2048);
    transpose_cvt<<<dim3(16, 64), dim3(32, 8), 0, stream>>>(wk, 512, 2048, 512, wqkvT + (size_t)2048 * 2048, 2048);
    transpose_cvt<<<dim3(16, 64), dim3(32, 8), 0, stream>>>(wv, 512, 2048, 512, wqkvT + (size_t)2560 * 2048, 2048);
    transpose_cvt<<<dim3(64, 64), dim3(32, 8), 0, stream>>>(wo, 2048, 2048, 2048, woT, 2048);
    // fused QKV projection + rope + rmsnorm -> Qn, Kn, Vbuf
    gemm_qkv<<<dim3(24, 32), 256, 0, stream>>>(xb, wqkvT, cosb, sinb, Qn, Kn, Vbuf);
    // V transpose -> Vt [512][4096] bf16
    transpose_cvt<<<dim3(16, 128), dim3(32, 8), 0, stream>>>(Vbuf, 512, 4096, 512, Vt, 4096);
    flash_attn<<<dim3(32, 16), 256, 0, stream>>>(Qn, Kn, Vt, Ao);
    gemm_bt_db<<<dim3(16, 32), 256, 0, stream>>>(Ao, woT, out, 4096, 2048, 2048);
}

// Round 7
// 363.795 us; speedup vs baseline: 2.6426x; 1.0252x over previous
//
#include <hip/hip_runtime.h>

#define T_SEQ 4096
#define C_EMB 2048
#define NH 16
#define NKV 4
#define HD 128

typedef short bf16x8 __attribute__((ext_vector_type(8)));
typedef float f32x4 __attribute__((ext_vector_type(4)));
typedef unsigned short u16x4 __attribute__((ext_vector_type(4)));

__device__ inline unsigned short f2bf(float f) {
    unsigned int u = __float_as_uint(f);
    unsigned int r = (u + 0x7FFFu + ((u >> 16) & 1u)) >> 16;
    return (unsigned short)r;
}

// async global->LDS 16B per lane; lds base must be wave-uniform (lane*16 auto-added)
__device__ __forceinline__ void async_cp16(const unsigned short* g, unsigned short* l) {
    __builtin_amdgcn_global_load_lds((const __attribute__((address_space(1))) unsigned int*)g,
                                     (__attribute__((address_space(3))) unsigned int*)l,
                                     16, 0, 0);
}

// ---------------- fp32 -> bf16 elementwise ----------------
__global__ __launch_bounds__(256) void cvt_bf16(const float* __restrict__ in,
                                                unsigned short* __restrict__ out, int n) {
    int i = (blockIdx.x * 256 + threadIdx.x) * 4;
    if (i >= n) return;
    float4 f = *(const float4*)(&in[i]);
    u16x4 o;
    o.x = f2bf(f.x); o.y = f2bf(f.y); o.z = f2bf(f.z); o.w = f2bf(f.w);
    *(u16x4*)(&out[i]) = o;
}

// ---------------- merged weight transposes: 4 matrices in one launch ----------------
__global__ __launch_bounds__(256) void transpose_all(const float* __restrict__ wq,
                                                     const float* __restrict__ wk,
                                                     const float* __restrict__ wv,
                                                     const float* __restrict__ wo,
                                                     unsigned short* __restrict__ wqkvT,
                                                     unsigned short* __restrict__ woT) {
    __shared__ float tile[32][33];
    int z = blockIdx.z;
    const float* in;
    unsigned short* out;
    int ld_in;
    if (z == 0)      { in = wq; out = wqkvT;                         ld_in = 2048; }
    else if (z == 1) { in = wk; out = wqkvT + (size_t)2048 * 2048;   ld_in = 512;  }
    else if (z == 2) { in = wv; out = wqkvT + (size_t)2560 * 2048;   ld_in = 512;  }
    else             { in = wo; out = woT;                           ld_in = 2048; }
    if ((z == 1 || z == 2) && blockIdx.x >= 16) return;

    int x = blockIdx.x * 32 + threadIdx.x;
    for (int i = threadIdx.y; i < 32; i += 8) {
        int y = blockIdx.y * 32 + i;
        tile[i][threadIdx.x] = in[(size_t)y * ld_in + x];
    }
    __syncthreads();
    int xo = blockIdx.y * 32 + threadIdx.x;
    for (int i = threadIdx.y; i < 32; i += 8) {
        int yo = blockIdx.x * 32 + i;
        out[(size_t)yo * 2048 + xo] = f2bf(tile[threadIdx.x][i]);
    }
}

// ==== Fused QKV projection + RoPE + RMSNorm + V-transpose ====
// 128x128 tile, BK=32 double-buffered (32KB LDS -> 4 blocks/CU), one barrier/iter.
// Wave tiling 1x4 (wave w: rows w*32..w*32+31, all 128 cols).
__global__ __launch_bounds__(256, 4) void gemm_qkv(const unsigned short* __restrict__ A,
                                                   const unsigned short* __restrict__ Bt,
                                                   const float* __restrict__ cosb,
                                                   const float* __restrict__ sinb,
                                                   unsigned short* __restrict__ Qn,
                                                   unsigned short* __restrict__ Kn,
                                                   unsigned short* __restrict__ Vt) {
    __shared__ __align__(16) unsigned short As[2][128 * 32];
    __shared__ __align__(16) unsigned short Bs[2][128 * 32];
    const int K = 2048;
    int t = threadIdx.x;
    int w = t >> 6, lane = t & 63;
    int ln = lane & 15, q = lane >> 4;
    int wm = w * 32;
    int m0 = blockIdx.y * 128, n0 = blockIdx.x * 128;

    f32x4 acc[2][8] = {};

#pragma unroll
    for (int s = 0; s < 2; ++s) {
        int L = s * 256 + t;
        int r = L >> 2;
        int c = (L & 3) ^ ((L >> 4) & 3);
        async_cp16(&A[(size_t)(m0 + r) * K + c * 8], &As[0][s * 2048 + w * 512]);
        async_cp16(&Bt[(size_t)(n0 + r) * K + c * 8], &Bs[0][s * 2048 + w * 512]);
    }

    for (int it = 0; it < 64; ++it) {
        __syncthreads();
        if (it < 63) {
            int k0 = (it + 1) * 32;
            int p = (it + 1) & 1;
#pragma unroll
            for (int s = 0; s < 2; ++s) {
                int L = s * 256 + t;
                int r = L >> 2;
                int c = (L & 3) ^ ((L >> 4) & 3);
                async_cp16(&A[(size_t)(m0 + r) * K + k0 + c * 8], &As[p][s * 2048 + w * 512]);
                async_cp16(&Bt[(size_t)(n0 + r) * K + k0 + c * 8], &Bs[p][s * 2048 + w * 512]);
            }
        }
        int p = it & 1;
        int cs = (q ^ ((ln >> 2) & 3)) * 8;
        bf16x8 af[2], bfr[8];
#pragma unroll
        for (int i = 0; i < 2; ++i) af[i] = *(const bf16x8*)(&As[p][(wm + i * 16 + ln) * 32 + cs]);
#pragma unroll
        for (int j = 0; j < 8; ++j) bfr[j] = *(const bf16x8*)(&Bs[p][(j * 16 + ln) * 32 + cs]);
#pragma unroll
        for (int i = 0; i < 2; ++i)
#pragma unroll
            for (int j = 0; j < 8; ++j)
                acc[i][j] = __builtin_amdgcn_mfma_f32_16x16x32_bf16(af[i], bfr[j], acc[i][j], 0, 0, 0);
    }

    // ---- fused epilogue ----
    if (n0 < 2560) {
        bool isQ = (n0 < 2048);
        int h = isQ ? (n0 >> 7) : ((n0 - 2048) >> 7);
#pragma unroll
        for (int i = 0; i < 2; ++i)
#pragma unroll
            for (int r = 0; r < 4; ++r) {
                int row = m0 + wm + i * 16 + q * 4 + r;
                float y1[4], y2[4];
                float ss = 0.0f;
#pragma unroll
                for (int j = 0; j < 4; ++j) {
                    float a = acc[i][j][r];
                    float b = acc[i][j + 4][r];
                    float cc = cosb[row * 64 + j * 16 + ln];
                    float sv = sinb[row * 64 + j * 16 + ln];
                    y1[j] = a * cc + b * sv;
                    y2[j] = b * cc - a * sv;
                    ss += y1[j] * y1[j] + y2[j] * y2[j];
                }
                ss += __shfl_xor(ss, 1);
                ss += __shfl_xor(ss, 2);
                ss += __shfl_xor(ss, 4);
                ss += __shfl_xor(ss, 8);
                float rv = rsqrtf(ss * (1.0f / 128.0f) + 1e-6f);
                if (isQ) {
                    float s = rv * (0.08838834764831845f * 1.4426950408889634f);
                    unsigned short* ob = Qn + (size_t)row * 2048 + h * 128;
#pragma unroll
                    for (int j = 0; j < 4; ++j) {
                        ob[j * 16 + ln] = f2bf(y1[j] * s);
                        ob[64 + j * 16 + ln] = f2bf(y2[j] * s);
                    }
                } else {
                    unsigned short* ob = Kn + (size_t)row * 512 + h * 128;
#pragma unroll
                    for (int j = 0; j < 4; ++j) {
                        ob[j * 16 + ln] = f2bf(y1[j] * rv);
                        ob[64 + j * 16 + ln] = f2bf(y2[j] * rv);
                    }
                }
            }
    } else {
        // V: transpose via LDS scratch (pitch 136 shorts = 272B, 16B-aligned rows),
        // 2 halves of 64 cols. Scratch spans As[0..]+Bs head: 8704 shorts < 16384.
        int v0 = n0 - 2560;
        unsigned short* sm = &As[0][0];
#pragma unroll
        for (int half = 0; half < 2; ++half) {
            __syncthreads();
#pragma unroll
            for (int i = 0; i < 2; ++i)
#pragma unroll
                for (int jj = 0; jj < 4; ++jj) {
                    int j = half * 4 + jj;
                    int cc = jj * 16 + ln;
                    int rr = wm + i * 16 + q * 4;
                    u16x4 pk;
                    pk.x = f2bf(acc[i][j][0]); pk.y = f2bf(acc[i][j][1]);
                    pk.z = f2bf(acc[i][j][2]); pk.w = f2bf(acc[i][j][3]);
                    *(u16x4*)(&sm[cc * 136 + rr]) = pk;
                }
            __syncthreads();
            // coalesced write out: 64 vt-rows x 128 m; each thread owns 32 shorts
            int vtr = t >> 2, mseg = (t & 3) * 32;
            unsigned short* dst = Vt + (size_t)(v0 + half * 64 + vtr) * 4096 + m0 + mseg;
            const unsigned short* src = &sm[vtr * 136 + mseg];
            *(int4*)(dst)      = *(const int4*)(src);
            *(int4*)(dst + 8)  = *(const int4*)(src + 8);
            *(int4*)(dst + 16) = *(const int4*)(src + 16);
            *(int4*)(dst + 24) = *(const int4*)(src + 24);
        }
    }
}

// ---------------- bf16 GEMM (out-proj): 128x128, BK=32 dbuf, 4 blocks/CU ----------------
__global__ __launch_bounds__(256, 4) void gemm_bt_db(const unsigned short* __restrict__ A,
                                                     const unsigned short* __restrict__ Bt,
                                                     float* __restrict__ C, int M, int N, int K) {
    __shared__ __align__(16) unsigned short As[2][128 * 32];
    __shared__ __align__(16) unsigned short Bs[2][128 * 32];
    int t = threadIdx.x;
    int w = t >> 6, lane = t & 63;
    int ln = lane & 15, q = lane >> 4;
    int wm = (w >> 1) * 64, wn = (w & 1) * 64;
    int m0 = blockIdx.y * 128, n0 = blockIdx.x * 128;

    f32x4 acc[4][4] = {};

#pragma unroll
    for (int s = 0; s < 2; ++s) {
        int L = s * 256 + t;
        int r = L >> 2;
        int c = (L & 3) ^ ((L >> 4) & 3);
        async_cp16(&A[(size_t)(m0 + r) * K + c * 8], &As[0][s * 2048 + w * 512]);
        async_cp16(&Bt[(size_t)(n0 + r) * K + c * 8], &Bs[0][s * 2048 + w * 512]);
    }

    int niter = K >> 5;
    for (int it = 0; it < niter; ++it) {
        __syncthreads();
        if (it < niter - 1) {
            int k0 = (it + 1) * 32;
            int p = (it + 1) & 1;
#pragma unroll
            for (int s = 0; s < 2; ++s) {
                int L = s * 256 + t;
                int r = L >> 2;
                int c = (L & 3) ^ ((L >> 4) & 3);
                async_cp16(&A[(size_t)(m0 + r) * K + k0 + c * 8], &As[p][s * 2048 + w * 512]);
                async_cp16(&Bt[(size_t)(n0 + r) * K + k0 + c * 8], &Bs[p][s * 2048 + w * 512]);
            }
        }
        int p = it & 1;
        int cs = (q ^ ((ln >> 2) & 3)) * 8;
        bf16x8 af[4], bfr[4];
#pragma unroll
        for (int i = 0; i < 4; ++i) af[i] = *(const bf16x8*)(&As[p][(wm + i * 16 + ln) * 32 + cs]);
#pragma unroll
        for (int j = 0; j < 4; ++j) bfr[j] = *(const bf16x8*)(&Bs[p][(wn + j * 16 + ln) * 32 + cs]);
#pragma unroll
        for (int i = 0; i < 4; ++i)
#pragma unroll
            for (int j = 0; j < 4; ++j)
                acc[i][j] = __builtin_amdgcn_mfma_f32_16x16x32_bf16(af[i], bfr[j], acc[i][j], 0, 0, 0);
    }
#pragma unroll
    for (int i = 0; i < 4; ++i)
#pragma unroll
        for (int j = 0; j < 4; ++j)
#pragma unroll
            for (int r = 0; r < 4; ++r) {
                int row = m0 + wm + i * 16 + q * 4 + r;
                int col = n0 + wn + j * 16 + ln;
                C[(size_t)row * N + col] = acc[i][j][r];
            }
}

// ---------------- Flash attention v4: fixed-max softmax (unchanged) ----------------
__global__ __launch_bounds__(256) void flash_attn(const unsigned short* __restrict__ Qn,
                                                  const unsigned short* __restrict__ Kn,
                                                  const unsigned short* __restrict__ Vt,
                                                  unsigned short* __restrict__ Ao) {
    __shared__ __align__(16) unsigned short Ks[2][64 * 128];
    __shared__ __align__(16) unsigned short Vs[2][128 * 64];
    __shared__ __align__(16) unsigned short Pl[4][16 * 72];

    int pairi = blockIdx.x;
    int h = blockIdx.y;
    int kvh = h >> 2;
    int t = threadIdx.x;
    int w = t >> 6, lane = t & 63;
    int ln = lane & 15, q = lane >> 4;

    int nA = 64 - pairi;
    int bq = 63 - pairi;
    int wq0 = bq * 64 + w * 16;

    bf16x8 qf[4];
    {
        const unsigned short* qb = Qn + (size_t)(wq0 + ln) * 2048 + h * 128;
#pragma unroll
        for (int kc = 0; kc < 4; ++kc) qf[kc] = *(const bf16x8*)(qb + kc * 32 + q * 8);
    }

    f32x4 o[8] = {};
    f32x4 l_p = {0.f, 0.f, 0.f, 0.f};

#pragma unroll
    for (int s = 0; s < 4; ++s) {
        int L = s * 256 + t;
        int key = L >> 4;
        int c = (L & 15) ^ (key & 15);
        async_cp16(Kn + (size_t)key * 512 + kvh * 128 + c * 8, &Ks[0][s * 2048 + w * 512]);
    }
#pragma unroll
    for (int s = 0; s < 4; ++s) {
        int L = s * 256 + t;
        int hd = L >> 3;
        int c = (L & 7) ^ (hd & 7);
        async_cp16(Vt + (size_t)(kvh * 128 + hd) * 4096 + c * 8, &Vs[0][s * 2048 + w * 512]);
    }

    for (int it = 0; it < 65; ++it) {
        __syncthreads();

        int nxt = it + 1;
        if (nxt < 65) {
            int nkt = (nxt < nA) ? nxt * 64 : (nxt - nA) * 64;
            unsigned short* kd = Ks[nxt & 1];
            unsigned short* vd = Vs[nxt & 1];
#pragma unroll
            for (int s = 0; s < 4; ++s) {
                int L = s * 256 + t;
                int key = L >> 4;
                int c = (L & 15) ^ (key & 15);
                async_cp16(Kn + (size_t)(nkt + key) * 512 + kvh * 128 + c * 8,
                           kd + s * 2048 + w * 512);
            }
#pragma unroll
            for (int s = 0; s < 4; ++s) {
                int L = s * 256 + t;
                int hd = L >> 3;
                int c = (L & 7) ^ (hd & 7);
                async_cp16(Vt + (size_t)(kvh * 128 + hd) * 4096 + nkt + c * 8,
                           vd + s * 2048 + w * 512);
            }
        }

        if (it == nA) {
#pragma unroll
            for (int r = 0; r < 4; ++r) {
                float lsum = l_p[r];
                lsum += __shfl_xor(lsum, 1);
                lsum += __shfl_xor(lsum, 2);
                lsum += __shfl_xor(lsum, 4);
                lsum += __shfl_xor(lsum, 8);
                float inv = 1.0f / lsum;
                int row = wq0 + q * 4 + r;
                unsigned short* ob = Ao + (size_t)row * 2048 + h * 128;
#pragma unroll
                for (int f = 0; f < 8; ++f) ob[f * 16 + ln] = f2bf(o[f][r] * inv);
            }
            bq = pairi;
            wq0 = bq * 64 + w * 16;
            const unsigned short* qb = Qn + (size_t)(wq0 + ln) * 2048 + h * 128;
#pragma unroll
            for (int kc = 0; kc < 4; ++kc) qf[kc] = *(const bf16x8*)(qb + kc * 32 + q * 8);
#pragma unroll
            for (int f = 0; f < 8; ++f) o[f] = (f32x4){0.f, 0.f, 0.f, 0.f};
            l_p = (f32x4){0.f, 0.f, 0.f, 0.f};
        }

        int kt0 = (it < nA) ? it * 64 : (it - nA) * 64;
        const unsigned short* kb = Ks[it & 1];
        const unsigned short* vb = Vs[it & 1];

        f32x4 sA[4] = {{-16.6f, -16.6f, -16.6f, -16.6f}, {-16.6f, -16.6f, -16.6f, -16.6f},
                       {-16.6f, -16.6f, -16.6f, -16.6f}, {-16.6f, -16.6f, -16.6f, -16.6f}};
#pragma unroll
        for (int jt = 0; jt < 4; ++jt) {
            int key = jt * 16 + ln;
#pragma unroll
            for (int kc = 0; kc < 4; ++kc) {
                int cs = ((kc * 4 + q) ^ ln) * 8;
                bf16x8 kf = *(const bf16x8*)(&kb[key * 128 + cs]);
                sA[jt] = __builtin_amdgcn_mfma_f32_16x16x32_bf16(qf[kc], kf, sA[jt], 0, 0, 0);
            }
        }
        if (kt0 + 63 > wq0) {
#pragma unroll
            for (int jt = 0; jt < 4; ++jt)
#pragma unroll
                for (int r = 0; r < 4; ++r) {
                    int key = kt0 + jt * 16 + ln;
                    int row = wq0 + q * 4 + r;
                    if (key > row) sA[jt][r] = -3e38f;
                }
        }
#pragma unroll
        for (int r = 0; r < 4; ++r) {
            int prow = (q * 4 + r) * 72;
#pragma unroll
            for (int jt = 0; jt < 4; ++jt) {
                float p = __builtin_amdgcn_exp2f(sA[jt][r]);
                Pl[w][prow + jt * 16 + ln] = (unsigned short)(__float_as_uint(p) >> 16);
                l_p[r] += p;
            }
        }

#pragma unroll
        for (int ks = 0; ks < 2; ++ks) {
            bf16x8 pa = *(const bf16x8*)(&Pl[w][ln * 72 + ks * 32 + q * 8]);
            int cs = ((ks * 4 + q) ^ (ln & 7)) * 8;
#pragma unroll
            for (int f = 0; f < 8; ++f) {
                bf16x8 vf = *(const bf16x8*)(&vb[(f * 16 + ln) * 64 + cs]);
                o[f] = __builtin_amdgcn_mfma_f32_16x16x32_bf16(pa, vf, o[f], 0, 0, 0);
            }
        }
    }
#pragma unroll
    for (int r = 0; r < 4; ++r) {
        float lsum = l_p[r];
        lsum += __shfl_xor(lsum, 1);
        lsum += __shfl_xor(lsum, 2);
        lsum += __shfl_xor(lsum, 4);
        lsum += __shfl_xor(lsum, 8);
        float inv = 1.0f / lsum;
        int row = wq0 + q * 4 + r;
        unsigned short* ob = Ao + (size_t)row * 2048 + h * 128;
#pragma unroll
        for (int f = 0; f < 8; ++f) ob[f * 16 + ln] = f2bf(o[f][r] * inv);
    }
}

extern "C" void kernel_launch(void* const* d_in, const int* in_sizes, int n_in,
                              void* d_out, int out_size, void* d_ws, size_t ws_size,
                              hipStream_t stream) {
    const float* x    = (const float*)d_in[0];
    const float* cosb = (const float*)d_in[1];
    const float* sinb = (const float*)d_in[2];
    const float* wq   = (const float*)d_in[3];
    const float* wk   = (const float*)d_in[4];
    const float* wv   = (const float*)d_in[5];
    const float* wo   = (const float*)d_in[6];
    float* out = (float*)d_out;

    char* ws = (char*)d_ws;
    unsigned short* xb    = (unsigned short*)ws;               // [4096][2048]
    unsigned short* wqkvT = xb    + (size_t)4096 * 2048;       // [3072][2048]
    unsigned short* woT   = wqkvT + (size_t)3072 * 2048;       // [2048][2048]
    unsigned short* Qn    = woT   + (size_t)2048 * 2048;       // [4096][2048]
    unsigned short* Kn    = Qn    + (size_t)4096 * 2048;       // [4096][512]
    unsigned short* Vt    = Kn    + (size_t)4096 * 512;        // [512][4096]
    unsigned short* Ao    = Vt    + (size_t)512 * 4096;        // [4096][2048]

    cvt_bf16<<<(4096 * 2048 / 4 + 255) / 256, 256, 0, stream>>>(x, xb, 4096 * 2048);
    transpose_all<<<dim3(64, 64, 4), dim3(32, 8), 0, stream>>>(wq, wk, wv, wo, wqkvT, woT);
    gemm_qkv<<<dim3(24, 32), 256, 0, stream>>>(xb, wqkvT, cosb, sinb, Qn, Kn, Vt);
    flash_attn<<<dim3(32, 16), 256, 0, stream>>>(Qn, Kn, Vt, Ao);
    gemm_bt_db<<<dim3(16, 32), 256, 0, stream>>>(Ao, woT, out, 4096, 2048, 2048);
}